// Round 10
// baseline (530.417 us; speedup 1.0000x reference)
//
#include <hip/hip_runtime.h>

__device__ __forceinline__ float leaky(float v) { return v >= 0.f ? v : 0.01f * v; }

__device__ __forceinline__ void fma4(float4& a, float s, const float4& w) {
    a.x = fmaf(s, w.x, a.x); a.y = fmaf(s, w.y, a.y);
    a.z = fmaf(s, w.z, a.z); a.w = fmaf(s, w.w, a.w);
}

__device__ __forceinline__ unsigned short f2bf(float x) {  // RNE
    unsigned b = __float_as_uint(x);
    return (unsigned short)((b + 0x7FFFu + ((b >> 16) & 1u)) >> 16);
}
__device__ __forceinline__ float bf2f(unsigned short u) {
    return __uint_as_float(((unsigned)u) << 16);
}

typedef __attribute__((ext_vector_type(8))) short short8v;
typedef __attribute__((ext_vector_type(4))) float float4v;

// ---------------------------------------------------------------------------
// CSR build (unchanged)
__global__ void k_deg(const int* __restrict__ col, int E, int* __restrict__ deg) {
    int e = blockIdx.x * blockDim.x + threadIdx.x;
    if (e < E) atomicAdd(&deg[col[e]], 1);
}

__global__ __launch_bounds__(256) void k_scan_part(const int* __restrict__ deg,
                                                   int* __restrict__ part,
                                                   int* __restrict__ bsum, int N) {
    __shared__ int tmp[256];
    int tid = threadIdx.x;
    int i = blockIdx.x * 256 + tid;
    int v = (i < N) ? deg[i] : 0;
    tmp[tid] = v;
    __syncthreads();
    for (int ofs = 1; ofs < 256; ofs <<= 1) {
        int t = (tid >= ofs) ? tmp[tid - ofs] : 0;
        __syncthreads();
        tmp[tid] += t;
        __syncthreads();
    }
    int incl = tmp[tid];
    if (i < N) part[i] = incl - v;
    if (tid == 255) bsum[blockIdx.x] = incl;
}

__global__ __launch_bounds__(256) void k_scan_sums(const int* __restrict__ bsum,
                                                   int* __restrict__ boff, int NB,
                                                   int* __restrict__ offs_last) {
    __shared__ int tmp[256];
    int tid = threadIdx.x;
    int v = (tid < NB) ? bsum[tid] : 0;
    tmp[tid] = v;
    __syncthreads();
    for (int ofs = 1; ofs < 256; ofs <<= 1) {
        int t = (tid >= ofs) ? tmp[tid - ofs] : 0;
        __syncthreads();
        tmp[tid] += t;
        __syncthreads();
    }
    int incl = tmp[tid];
    if (tid < NB) boff[tid] = incl - v;
    if (tid == 255) offs_last[0] = incl;
}

__global__ __launch_bounds__(256) void k_scan_final(const int* __restrict__ part,
                                                    const int* __restrict__ boff,
                                                    const int* __restrict__ deg,
                                                    int* __restrict__ offs,
                                                    int* __restrict__ pos,
                                                    float* __restrict__ dinv, int N) {
    int i = blockIdx.x * 256 + threadIdx.x;
    if (i < N) {
        int o = part[i] + boff[blockIdx.x];
        offs[i] = o;
        pos[i] = o;
        dinv[i] = rsqrtf((float)(deg[i] + 1));
    }
}

__global__ void k_fill(const int* __restrict__ row, const int* __restrict__ col, int E,
                       int* __restrict__ pos, int* __restrict__ csr) {
    int e = blockIdx.x * blockDim.x + threadIdx.x;
    if (e < E) {
        int p = atomicAdd(&pos[col[e]], 1);
        csr[p] = row[e];
    }
}

// ---------------------------------------------------------------------------
// Phase A — MFMA + 4-deep register prefetch ring. waves_per_eu(4,6) raises the
// VGPR budget to ~128 so the ring is NOT collapsed by the allocator (R8/R9
// compiled to 40 VGPRs -> ring sunk to just-in-time loads -> latency-bound).
__global__ __attribute__((amdgpu_waves_per_eu(4, 6))) __launch_bounds__(512)
void k_featB(
    const float* __restrict__ s, const float* __restrict__ d, const float* __restrict__ t,
    const float* __restrict__ Ws, const float* __restrict__ bs2,
    const float* __restrict__ Wd, const float* __restrict__ bd2,
    const float* __restrict__ Wt, const float* __restrict__ bt2,
    const float* __restrict__ prof, const float* __restrict__ pers,
    const float* __restrict__ Wp, const float* __restrict__ bp,
    const float* __restrict__ Wpe, const float* __restrict__ bpe,
    float* __restrict__ x1g, int N, int NG) {
    __shared__ short8v wfv[3072];  // [hi:1536][lo:1536] fragments, 48 KB

    const int bid = blockIdx.x;
    const int tid = threadIdx.x;

    if (bid >= 3 * NG) {  // ---- fused tiny linears ----
        int n = (bid - 3 * NG) * 512 + tid;
        if (n >= N) return;
        float pv[5], pe[7];
#pragma unroll
        for (int i = 0; i < 5; ++i) pv[i] = prof[(size_t)n * 5 + i];
#pragma unroll
        for (int i = 0; i < 7; ++i) pe[i] = pers[(size_t)n * 7 + i];
        float o[16];
#pragma unroll
        for (int j = 0; j < 8; ++j) {
            float a = bp[j];
#pragma unroll
            for (int i = 0; i < 5; ++i) a = fmaf(pv[i], Wp[i * 8 + j], a);
            o[j] = leaky(a);
            float a2 = bpe[j];
#pragma unroll
            for (int i = 0; i < 7; ++i) a2 = fmaf(pe[i], Wpe[i * 8 + j], a2);
            o[8 + j] = leaky(a2);
        }
#pragma unroll
        for (int v = 0; v < 4; ++v)
            *reinterpret_cast<float4*>(x1g + (size_t)n * 64 + 48 + v * 4) =
                make_float4(o[v * 4], o[v * 4 + 1], o[v * 4 + 2], o[v * 4 + 3]);
        return;
    }

    const int f = bid / NG;
    const int grp = bid - f * NG;
    const float* __restrict__ X = (f == 0) ? s : ((f == 1) ? d : t);
    const float* __restrict__ W = (f == 0) ? Ws : ((f == 1) ? Wd : Wt);
    const float* __restrict__ B = (f == 0) ? bs2 : ((f == 1) ? bd2 : bt2);
    const int n0 = grp * 128;
    const int lane = tid & 63;
    const int wid = tid >> 6;  // 0..7

    short* wfs = (short*)wfv;
#pragma unroll
    for (int v = 0; v < 6; ++v) {
        int idx4 = tid + v * 512;          // 3072 float4 = 768x16
        float4 w4 = *reinterpret_cast<const float4*>(W + (size_t)idx4 * 4);
        int k = idx4 >> 2;
        int j0 = (idx4 & 3) * 4;
        int c = k >> 5, g = (k >> 3) & 3, i = k & 7;
        float wq[4] = {w4.x, w4.y, w4.z, w4.w};
#pragma unroll
        for (int q = 0; q < 4; ++q) {
            int sl = (c * 64 + g * 16 + j0 + q) * 8 + i;
            unsigned short h = f2bf(wq[q]);
            wfs[sl] = (short)h;
            wfs[12288 + sl] = (short)f2bf(wq[q] - bf2f(h));
        }
    }
    __syncthreads();

    const int nb = n0 + wid * 16;
    int mrow = nb + (lane & 15); if (mrow >= N) mrow = N - 1;
    const float* base = X + (size_t)mrow * 768 + ((lane >> 4) << 3);

    float4 pa[4], pb[4];
#pragma unroll
    for (int u = 0; u < 4; ++u) {
        pa[u] = *reinterpret_cast<const float4*>(base + u * 32);
        pb[u] = *reinterpret_cast<const float4*>(base + u * 32 + 4);
    }
    float4v acc = {0.f, 0.f, 0.f, 0.f};

#pragma unroll
    for (int c = 0; c < 24; ++c) {
        const int u = c & 3;
        float xs[8] = {pa[u].x, pa[u].y, pa[u].z, pa[u].w,
                       pb[u].x, pb[u].y, pb[u].z, pb[u].w};
        if (c + 4 < 24) {
            pa[u] = *reinterpret_cast<const float4*>(base + (c + 4) * 32);
            pb[u] = *reinterpret_cast<const float4*>(base + (c + 4) * 32 + 4);
        }
        short8v xh, xl;
#pragma unroll
        for (int i = 0; i < 8; ++i) {
            unsigned short h = f2bf(xs[i]);
            xh[i] = (short)h;
            xl[i] = (short)f2bf(xs[i] - bf2f(h));
        }
        short8v wh = wfv[c * 64 + lane];
        short8v wl = wfv[1536 + c * 64 + lane];
        acc = __builtin_amdgcn_mfma_f32_16x16x32_bf16(xh, wh, acc, 0, 0, 0);
        acc = __builtin_amdgcn_mfma_f32_16x16x32_bf16(xl, wh, acc, 0, 0, 0);
        acc = __builtin_amdgcn_mfma_f32_16x16x32_bf16(xh, wl, acc, 0, 0, 0);
    }

    int j = lane & 15;
    float bb = B[j];
#pragma unroll
    for (int r = 0; r < 4; ++r) {
        int n = nb + ((lane >> 4) << 2) + r;
        if (n < N) x1g[(size_t)n * 64 + f * 16 + j] = leaky(acc[r] + bb);
    }
}

// ---------------------------------------------------------------------------
// Fused lin + gcn1-matmul (unchanged from R9)
__global__ __launch_bounds__(256) void k_lin1(const float* __restrict__ x1,
                                              const float* __restrict__ Wl,
                                              const float* __restrict__ bl,
                                              const float* __restrict__ Wg1,
                                              const float* __restrict__ dinvv,
                                              unsigned short* __restrict__ z, int N) {
    __shared__ float4 xt4[1024];
    __shared__ float4 wt4[1024];
    const int tid = threadIdx.x;
    const int n0 = blockIdx.x * 64;
    const int nq = tid & 15;
    const int jq = tid >> 4;

#pragma unroll
    for (int v = 0; v < 4; ++v) {
        int L = v * 256 + tid;
        int n = L >> 4, c4 = L & 15;
        int nn = n0 + n; if (nn >= N) nn = N - 1;
        xt4[n * 16 + (c4 ^ (n & 15))] = *reinterpret_cast<const float4*>(x1 + (size_t)nn * 64 + c4 * 4);
        wt4[L] = *reinterpret_cast<const float4*>(Wl + (size_t)L * 4);
    }
    __syncthreads();

    float4 acc[4];
#pragma unroll
    for (int g = 0; g < 4; ++g) acc[g] = make_float4(0.f, 0.f, 0.f, 0.f);
    for (int k = 0; k < 64; k += 4) {
        float4 w0 = wt4[(k + 0) * 16 + jq];
        float4 w1 = wt4[(k + 1) * 16 + jq];
        float4 w2 = wt4[(k + 2) * 16 + jq];
        float4 w3 = wt4[(k + 3) * 16 + jq];
        int k4 = k >> 2;
#pragma unroll
        for (int g = 0; g < 4; ++g) {
            int n = nq + (g << 4);
            float4 xv = xt4[n * 16 + (k4 ^ (n & 15))];
            fma4(acc[g], xv.x, w0);
            fma4(acc[g], xv.y, w1);
            fma4(acc[g], xv.z, w2);
            fma4(acc[g], xv.w, w3);
        }
    }
    float4 bb = *reinterpret_cast<const float4*>(bl + jq * 4);
    __syncthreads();

#pragma unroll
    for (int g = 0; g < 4; ++g) {
        int n = nq + (g << 4);
        float4 h;
        h.x = leaky(acc[g].x + bb.x);
        h.y = leaky(acc[g].y + bb.y);
        h.z = leaky(acc[g].z + bb.z);
        h.w = leaky(acc[g].w + bb.w);
        xt4[n * 16 + (jq ^ (n & 15))] = h;
    }
#pragma unroll
    for (int v = 0; v < 4; ++v) {
        int L = v * 256 + tid;
        wt4[L] = *reinterpret_cast<const float4*>(Wg1 + (size_t)L * 4);
    }
    __syncthreads();

#pragma unroll
    for (int g = 0; g < 4; ++g) acc[g] = make_float4(0.f, 0.f, 0.f, 0.f);
    for (int k = 0; k < 64; k += 4) {
        float4 w0 = wt4[(k + 0) * 16 + jq];
        float4 w1 = wt4[(k + 1) * 16 + jq];
        float4 w2 = wt4[(k + 2) * 16 + jq];
        float4 w3 = wt4[(k + 3) * 16 + jq];
        int k4 = k >> 2;
#pragma unroll
        for (int g = 0; g < 4; ++g) {
            int n = nq + (g << 4);
            float4 xv = xt4[n * 16 + (k4 ^ (n & 15))];
            fma4(acc[g], xv.x, w0);
            fma4(acc[g], xv.y, w1);
            fma4(acc[g], xv.z, w2);
            fma4(acc[g], xv.w, w3);
        }
    }
#pragma unroll
    for (int g = 0; g < 4; ++g) {
        int n = nq + (g << 4);
        if (n0 + n >= N) continue;
        float dv = dinvv[n0 + n];
        ushort4 o;
        o.x = f2bf(acc[g].x * dv); o.y = f2bf(acc[g].y * dv);
        o.z = f2bf(acc[g].z * dv); o.w = f2bf(acc[g].w * dv);
        *reinterpret_cast<ushort4*>(z + (size_t)(n0 + n) * 64 + jq * 4) = o;
    }
}

// ---------------------------------------------------------------------------
// Generic 64x64 node-matmul (layers 2,3; unchanged)
__global__ __launch_bounds__(256, 4) void k_mm64(const float* __restrict__ xin,
                                                 const float* __restrict__ W,
                                                 const float* __restrict__ dinvv,
                                                 unsigned short* __restrict__ z, int N) {
    __shared__ float4 xt4[1024];
    __shared__ float4 wt4[1024];
    const int tid = threadIdx.x;
    const int n0 = blockIdx.x * 64;
#pragma unroll
    for (int v = 0; v < 4; ++v) {
        int L = v * 256 + tid;
        int n = L >> 4, c4 = L & 15;
        int nn = n0 + n; if (nn >= N) nn = N - 1;
        xt4[n * 16 + (c4 ^ (n & 15))] = *reinterpret_cast<const float4*>(xin + (size_t)nn * 64 + c4 * 4);
        wt4[L] = *reinterpret_cast<const float4*>(W + (size_t)L * 4);
    }
    __syncthreads();
    const int nq = tid & 15;
    const int jq = tid >> 4;
    float4 acc[4];
#pragma unroll
    for (int g = 0; g < 4; ++g) acc[g] = make_float4(0.f, 0.f, 0.f, 0.f);
    for (int k = 0; k < 64; k += 4) {
        float4 w0 = wt4[(k + 0) * 16 + jq];
        float4 w1 = wt4[(k + 1) * 16 + jq];
        float4 w2 = wt4[(k + 2) * 16 + jq];
        float4 w3 = wt4[(k + 3) * 16 + jq];
        int k4 = k >> 2;
#pragma unroll
        for (int g = 0; g < 4; ++g) {
            int n = nq + (g << 4);
            float4 xv = xt4[n * 16 + (k4 ^ (n & 15))];
            fma4(acc[g], xv.x, w0);
            fma4(acc[g], xv.y, w1);
            fma4(acc[g], xv.z, w2);
            fma4(acc[g], xv.w, w3);
        }
    }
#pragma unroll
    for (int g = 0; g < 4; ++g) {
        int n = nq + (g << 4);
        if (n0 + n >= N) continue;
        float dv = dinvv[n0 + n];
        ushort4 o;
        o.x = f2bf(acc[g].x * dv); o.y = f2bf(acc[g].y * dv);
        o.z = f2bf(acc[g].z * dv); o.w = f2bf(acc[g].w * dv);
        *reinterpret_cast<ushort4*>(z + (size_t)(n0 + n) * 64 + jq * 4) = o;
    }
}

// ---------------------------------------------------------------------------
// Gather aggregation v3: quad-edge ushort4 gathers. quarter q = lane>>4 owns
// edge j+q; 16 lanes/row x 8 B = full 128 B row. 8 quads unrolled = 32 edges
// in flight. Quarters combined at the end with 2 shfl_xor per component.
__global__ __launch_bounds__(256) void k_agg(const unsigned short* __restrict__ z,
                                             const int* __restrict__ offs,
                                             const int* __restrict__ csr,
                                             const float* __restrict__ dinv,
                                             const float* __restrict__ bias,
                                             const float* __restrict__ x1,
                                             float* __restrict__ xout, int N) {
    int lane = threadIdx.x & 63;
    int c = blockIdx.x * 4 + (threadIdx.x >> 6);
    if (c >= N) return;
    int s = __builtin_amdgcn_readfirstlane(offs[c]);
    int e = __builtin_amdgcn_readfirstlane(offs[c + 1]);
    const int q = lane >> 4;   // edge slot 0..3
    const int d = lane & 15;   // feature quad: features 4d..4d+3
    const ushort4* __restrict__ zr = (const ushort4*)z;  // 16 per row

    float4 a = make_float4(0.f, 0.f, 0.f, 0.f);
    if (q == 0) {  // self-loop
        ushort4 v = zr[(size_t)c * 16 + d];
        a.x = bf2f(v.x); a.y = bf2f(v.y); a.z = bf2f(v.z); a.w = bf2f(v.w);
    }
    float4 u[8];
#pragma unroll
    for (int t = 0; t < 8; ++t) u[t] = make_float4(0.f, 0.f, 0.f, 0.f);

    int j = s;
    for (; j + 32 <= e; j += 32) {
#pragma unroll
        for (int t = 0; t < 8; ++t) {
            int r = csr[j + 4 * t + q];
            ushort4 v = zr[(size_t)r * 16 + d];
            u[t].x += bf2f(v.x); u[t].y += bf2f(v.y);
            u[t].z += bf2f(v.z); u[t].w += bf2f(v.w);
        }
    }
    for (; j + 4 <= e; j += 4) {
        int r = csr[j + q];
        ushort4 v = zr[(size_t)r * 16 + d];
        a.x += bf2f(v.x); a.y += bf2f(v.y); a.z += bf2f(v.z); a.w += bf2f(v.w);
    }
    if (j < e && q < e - j) {  // 1..3 leftover edges
        int r = csr[j + q];
        ushort4 v = zr[(size_t)r * 16 + d];
        a.x += bf2f(v.x); a.y += bf2f(v.y); a.z += bf2f(v.z); a.w += bf2f(v.w);
    }
    float tx = a.x + ((u[0].x + u[1].x) + (u[2].x + u[3].x)) + ((u[4].x + u[5].x) + (u[6].x + u[7].x));
    float ty = a.y + ((u[0].y + u[1].y) + (u[2].y + u[3].y)) + ((u[4].y + u[5].y) + (u[6].y + u[7].y));
    float tz = a.z + ((u[0].z + u[1].z) + (u[2].z + u[3].z)) + ((u[4].z + u[5].z) + (u[6].z + u[7].z));
    float tw = a.w + ((u[0].w + u[1].w) + (u[2].w + u[3].w)) + ((u[4].w + u[5].w) + (u[6].w + u[7].w));
    tx += __shfl_xor(tx, 16); tx += __shfl_xor(tx, 32);
    ty += __shfl_xor(ty, 16); ty += __shfl_xor(ty, 32);
    tz += __shfl_xor(tz, 16); tz += __shfl_xor(tz, 32);
    tw += __shfl_xor(tw, 16); tw += __shfl_xor(tw, 32);
    if (q == 0) {
        float dv = dinv[c];
        float4 bb = reinterpret_cast<const float4*>(bias)[d];
        float4 xx = *reinterpret_cast<const float4*>(x1 + (size_t)c * 64 + 4 * d);
        float4 o;
        o.x = dv * tx + bb.x + xx.x;
        o.y = dv * ty + bb.y + xx.y;
        o.z = dv * tz + bb.z + xx.z;
        o.w = dv * tw + bb.w + xx.w;
        *reinterpret_cast<float4*>(xout + (size_t)c * 64 + 4 * d) = o;
    }
}

// ---------------------------------------------------------------------------
// head (unchanged)
__global__ __launch_bounds__(256) void k_head(const float* __restrict__ xin,
                                              const float* __restrict__ Wo1,
                                              const float* __restrict__ bo1,
                                              const float* __restrict__ Wo2,
                                              const float* __restrict__ bo2,
                                              float* __restrict__ out, int N) {
    __shared__ float xsg[64][65];
    __shared__ float wg[64][65];
    __shared__ float hs[64][65];
    __shared__ float wo2[128];
    const int tid = threadIdx.x;
    const int n0 = blockIdx.x * 64;
#pragma unroll
    for (int v = 0; v < 4; ++v) {
        int idx = tid + v * 256;
        int n = idx >> 4;
        int jj = (idx & 15) << 2;
        float4 xv = make_float4(0.f, 0.f, 0.f, 0.f);
        if (n0 + n < N) xv = *reinterpret_cast<const float4*>(xin + (size_t)(n0 + n) * 64 + jj);
        xsg[n][jj] = xv.x; xsg[n][jj + 1] = xv.y; xsg[n][jj + 2] = xv.z; xsg[n][jj + 3] = xv.w;
        float4 w = *reinterpret_cast<const float4*>(Wo1 + (size_t)n * 64 + jj);
        wg[n][jj] = w.x; wg[n][jj + 1] = w.y; wg[n][jj + 2] = w.z; wg[n][jj + 3] = w.w;
    }
    if (tid < 128) wo2[tid] = Wo2[tid];
    __syncthreads();
    int j = tid & 63;
    int g = tid >> 6;
    float bj = bo1[j];
    for (int i = 0; i < 16; ++i) {
        int n = g * 16 + i;
        float a = bj;
#pragma unroll
        for (int k = 0; k < 64; ++k) a += xsg[n][k] * wg[k][j];
        hs[n][j] = leaky(a);
    }
    __syncthreads();
    if (tid < 128) {
        int n = tid >> 1;
        int j2 = tid & 1;
        float a = bo2[j2];
#pragma unroll
        for (int k = 0; k < 64; ++k) a += hs[n][k] * wo2[k * 2 + j2];
        if (n0 + n < N) out[(size_t)(n0 + n) * 2 + j2] = 1.f / (1.f + expf(-a));
    }
}

// ---------------------------------------------------------------------------
extern "C" void kernel_launch(void* const* d_in, const int* in_sizes, int n_in,
                              void* d_out, int out_size, void* d_ws, size_t ws_size,
                              hipStream_t stream) {
    const float* screen   = (const float*)d_in[0];
    const float* des      = (const float*)d_in[1];
    const float* tweet    = (const float*)d_in[2];
    const float* profile  = (const float*)d_in[3];
    const float* personal = (const float*)d_in[4];
    const int*   edge     = (const int*)d_in[5];
    const float* Ws  = (const float*)d_in[6],  *bs  = (const float*)d_in[7];
    const float* Wd  = (const float*)d_in[8],  *bd  = (const float*)d_in[9];
    const float* Wt  = (const float*)d_in[10], *bt  = (const float*)d_in[11];
    const float* Wp  = (const float*)d_in[12], *bp  = (const float*)d_in[13];
    const float* Wpe = (const float*)d_in[14], *bpe = (const float*)d_in[15];
    const float* Wl  = (const float*)d_in[16], *bl  = (const float*)d_in[17];
    const float* Wg1 = (const float*)d_in[18], *bg1 = (const float*)d_in[19];
    const float* Wg2 = (const float*)d_in[20], *bg2 = (const float*)d_in[21];
    const float* Wg3 = (const float*)d_in[22], *bg3 = (const float*)d_in[23];
    const float* Wo1 = (const float*)d_in[24], *bo1 = (const float*)d_in[25];
    const float* Wo2 = (const float*)d_in[26], *bo2 = (const float*)d_in[27];

    const int N = in_sizes[0] / 768;   // 50000
    const int E = in_sizes[5] / 2;     // 1600000
    const int* row = edge;
    const int* col = edge + E;

    size_t off = 0;
    auto alloc = [&](size_t bytes) -> void* {
        void* p = (char*)d_ws + off;
        off += (bytes + 255) & ~(size_t)255;
        return p;
    };
    const size_t NF = (size_t)N * 64;
    float* x1   = (float*)alloc(NF * 4);
    float* xa   = (float*)alloc(NF * 4);
    float* xb   = (float*)alloc(NF * 4);
    unsigned short* z = (unsigned short*)alloc(NF * 2);
    float* dinv = (float*)alloc((size_t)N * 4);
    int* deg  = (int*)alloc((size_t)N * 4);
    int* part = (int*)alloc((size_t)N * 4);
    int* offs = (int*)alloc((size_t)(N + 1) * 4);
    int* pos  = (int*)alloc((size_t)N * 4);
    int* csr  = (int*)alloc((size_t)E * 4);
    const int NB = (N + 255) / 256;
    int* bsum = (int*)alloc((size_t)NB * 4);
    int* boff = (int*)alloc((size_t)NB * 4);
    (void)ws_size; (void)n_in; (void)out_size;

    // CSR build
    hipMemsetAsync(deg, 0, (size_t)N * 4, stream);
    k_deg<<<(E + 255) / 256, 256, 0, stream>>>(col, E, deg);
    k_scan_part<<<NB, 256, 0, stream>>>(deg, part, bsum, N);
    k_scan_sums<<<1, 256, 0, stream>>>(bsum, boff, NB, offs + N);
    k_scan_final<<<NB, 256, 0, stream>>>(part, boff, deg, offs, pos, dinv, N);
    k_fill<<<(E + 255) / 256, 256, 0, stream>>>(row, col, E, pos, csr);

    // Phase A: MFMA feature linears + fused tiny linears
    const int NG = (N + 127) / 128;
    const int NSM = (N + 511) / 512;
    k_featB<<<NG * 3 + NSM, 512, 0, stream>>>(screen, des, tweet,
                                              Ws, bs, Wd, bd, Wt, bt,
                                              profile, personal, Wp, bp, Wpe, bpe,
                                              x1, N, NG);

    const int NGB = (N + 63) / 64;
    const int NAB = (N + 3) / 4;
    // layer 1 (lin + matmul fused)
    k_lin1<<<NGB, 256, 0, stream>>>(x1, Wl, bl, Wg1, dinv, z, N);
    k_agg<<<NAB, 256, 0, stream>>>(z, offs, csr, dinv, bg1, x1, xb, N);
    // layer 2
    k_mm64<<<NGB, 256, 0, stream>>>(xb, Wg2, dinv, z, N);
    k_agg<<<NAB, 256, 0, stream>>>(z, offs, csr, dinv, bg2, x1, xa, N);
    // layer 3
    k_mm64<<<NGB, 256, 0, stream>>>(xa, Wg3, dinv, z, N);
    k_agg<<<NAB, 256, 0, stream>>>(z, offs, csr, dinv, bg3, x1, xb, N);

    // head
    k_head<<<NGB, 256, 0, stream>>>(xb, Wo1, bo1, Wo2, bo2, (float*)d_out, N);
}

// Round 11
// 475.259 us; speedup vs baseline: 1.1161x; 1.1161x over previous
//
#include <hip/hip_runtime.h>

__device__ __forceinline__ float leaky(float v) { return v >= 0.f ? v : 0.01f * v; }

__device__ __forceinline__ void fma4(float4& a, float s, const float4& w) {
    a.x = fmaf(s, w.x, a.x); a.y = fmaf(s, w.y, a.y);
    a.z = fmaf(s, w.z, a.z); a.w = fmaf(s, w.w, a.w);
}

__device__ __forceinline__ unsigned short f2bf(float x) {  // RNE
    unsigned b = __float_as_uint(x);
    return (unsigned short)((b + 0x7FFFu + ((b >> 16) & 1u)) >> 16);
}
__device__ __forceinline__ float bf2f(unsigned short u) {
    return __uint_as_float(((unsigned)u) << 16);
}

typedef __attribute__((ext_vector_type(8))) short short8v;
typedef __attribute__((ext_vector_type(4))) float float4v;

// ---------------------------------------------------------------------------
// Scan kernels (unchanged)
__global__ __launch_bounds__(256) void k_scan_part(const int* __restrict__ deg,
                                                   int* __restrict__ part,
                                                   int* __restrict__ bsum, int N) {
    __shared__ int tmp[256];
    int tid = threadIdx.x;
    int i = blockIdx.x * 256 + tid;
    int v = (i < N) ? deg[i] : 0;
    tmp[tid] = v;
    __syncthreads();
    for (int ofs = 1; ofs < 256; ofs <<= 1) {
        int t = (tid >= ofs) ? tmp[tid - ofs] : 0;
        __syncthreads();
        tmp[tid] += t;
        __syncthreads();
    }
    int incl = tmp[tid];
    if (i < N) part[i] = incl - v;
    if (tid == 255) bsum[blockIdx.x] = incl;
}

__global__ __launch_bounds__(256) void k_scan_sums(const int* __restrict__ bsum,
                                                   int* __restrict__ boff, int NB,
                                                   int* __restrict__ offs_last) {
    __shared__ int tmp[256];
    int tid = threadIdx.x;
    int v = (tid < NB) ? bsum[tid] : 0;
    tmp[tid] = v;
    __syncthreads();
    for (int ofs = 1; ofs < 256; ofs <<= 1) {
        int t = (tid >= ofs) ? tmp[tid - ofs] : 0;
        __syncthreads();
        tmp[tid] += t;
        __syncthreads();
    }
    int incl = tmp[tid];
    if (tid < NB) boff[tid] = incl - v;
    if (tid == 255) offs_last[0] = incl;
}

__global__ __launch_bounds__(256) void k_scan_final(const int* __restrict__ part,
                                                    const int* __restrict__ boff,
                                                    const int* __restrict__ deg,
                                                    int* __restrict__ offs,
                                                    int* __restrict__ pos,
                                                    float* __restrict__ dinv, int N) {
    int i = blockIdx.x * 256 + threadIdx.x;
    if (i < N) {
        int o = part[i] + boff[blockIdx.x];
        offs[i] = o;
        pos[i] = o;
        dinv[i] = rsqrtf((float)(deg[i] + 1));
    }
}

// ---------------------------------------------------------------------------
// Phase A — MFMA featB (R8 structure) + fused tiny linears + fused k_deg
// tail blocks (edge-degree atomics ride in featB's memory-stall bubbles).
__global__ __launch_bounds__(512) void k_featB(
    const float* __restrict__ s, const float* __restrict__ d, const float* __restrict__ t,
    const float* __restrict__ Ws, const float* __restrict__ bs2,
    const float* __restrict__ Wd, const float* __restrict__ bd2,
    const float* __restrict__ Wt, const float* __restrict__ bt2,
    const float* __restrict__ prof, const float* __restrict__ pers,
    const float* __restrict__ Wp, const float* __restrict__ bp,
    const float* __restrict__ Wpe, const float* __restrict__ bpe,
    const int* __restrict__ colv, int* __restrict__ deg, int E,
    float* __restrict__ x1g, int N, int NG, int NSM) {
    __shared__ short8v wfv[3072];  // [hi:1536][lo:1536] fragments, 48 KB

    const int bid = blockIdx.x;
    const int tid = threadIdx.x;

    if (bid >= 3 * NG + NSM) {  // ---- fused degree count ----
        int e = (bid - 3 * NG - NSM) * 512 + tid;
        if (e < E) atomicAdd(&deg[colv[e]], 1);
        return;
    }

    if (bid >= 3 * NG) {  // ---- fused tiny linears ----
        int n = (bid - 3 * NG) * 512 + tid;
        if (n >= N) return;
        float pv[5], pe[7];
#pragma unroll
        for (int i = 0; i < 5; ++i) pv[i] = prof[(size_t)n * 5 + i];
#pragma unroll
        for (int i = 0; i < 7; ++i) pe[i] = pers[(size_t)n * 7 + i];
        float o[16];
#pragma unroll
        for (int j = 0; j < 8; ++j) {
            float a = bp[j];
#pragma unroll
            for (int i = 0; i < 5; ++i) a = fmaf(pv[i], Wp[i * 8 + j], a);
            o[j] = leaky(a);
            float a2 = bpe[j];
#pragma unroll
            for (int i = 0; i < 7; ++i) a2 = fmaf(pe[i], Wpe[i * 8 + j], a2);
            o[8 + j] = leaky(a2);
        }
#pragma unroll
        for (int v = 0; v < 4; ++v)
            *reinterpret_cast<float4*>(x1g + (size_t)n * 64 + 48 + v * 4) =
                make_float4(o[v * 4], o[v * 4 + 1], o[v * 4 + 2], o[v * 4 + 3]);
        return;
    }

    const int f = bid / NG;
    const int grp = bid - f * NG;
    const float* __restrict__ X = (f == 0) ? s : ((f == 1) ? d : t);
    const float* __restrict__ W = (f == 0) ? Ws : ((f == 1) ? Wd : Wt);
    const float* __restrict__ B = (f == 0) ? bs2 : ((f == 1) ? bd2 : bt2);
    const int n0 = grp * 128;
    const int lane = tid & 63;
    const int wid = tid >> 6;  // 0..7

    short* wfs = (short*)wfv;
#pragma unroll
    for (int v = 0; v < 6; ++v) {
        int idx4 = tid + v * 512;          // 3072 float4 = 768x16
        float4 w4 = *reinterpret_cast<const float4*>(W + (size_t)idx4 * 4);
        int k = idx4 >> 2;
        int j0 = (idx4 & 3) * 4;
        int c = k >> 5, g = (k >> 3) & 3, i = k & 7;
        float wq[4] = {w4.x, w4.y, w4.z, w4.w};
#pragma unroll
        for (int q = 0; q < 4; ++q) {
            int sl = (c * 64 + g * 16 + j0 + q) * 8 + i;
            unsigned short h = f2bf(wq[q]);
            wfs[sl] = (short)h;
            wfs[12288 + sl] = (short)f2bf(wq[q] - bf2f(h));
        }
    }
    __syncthreads();

    const int nb = n0 + wid * 16;
    int mrow = nb + (lane & 15); if (mrow >= N) mrow = N - 1;
    const float* base = X + (size_t)mrow * 768 + ((lane >> 4) << 3);

    float4 pa[4], pb[4];
#pragma unroll
    for (int u = 0; u < 4; ++u) {
        pa[u] = *reinterpret_cast<const float4*>(base + u * 32);
        pb[u] = *reinterpret_cast<const float4*>(base + u * 32 + 4);
    }
    float4v acc = {0.f, 0.f, 0.f, 0.f};

#pragma unroll
    for (int c = 0; c < 24; ++c) {
        const int u = c & 3;
        float xs[8] = {pa[u].x, pa[u].y, pa[u].z, pa[u].w,
                       pb[u].x, pb[u].y, pb[u].z, pb[u].w};
        if (c + 4 < 24) {
            pa[u] = *reinterpret_cast<const float4*>(base + (c + 4) * 32);
            pb[u] = *reinterpret_cast<const float4*>(base + (c + 4) * 32 + 4);
        }
        short8v xh, xl;
#pragma unroll
        for (int i = 0; i < 8; ++i) {
            unsigned short h = f2bf(xs[i]);
            xh[i] = (short)h;
            xl[i] = (short)f2bf(xs[i] - bf2f(h));
        }
        short8v wh = wfv[c * 64 + lane];
        short8v wl = wfv[1536 + c * 64 + lane];
        acc = __builtin_amdgcn_mfma_f32_16x16x32_bf16(xh, wh, acc, 0, 0, 0);
        acc = __builtin_amdgcn_mfma_f32_16x16x32_bf16(xl, wh, acc, 0, 0, 0);
        acc = __builtin_amdgcn_mfma_f32_16x16x32_bf16(xh, wl, acc, 0, 0, 0);
    }

    int j = lane & 15;
    float bb = B[j];
#pragma unroll
    for (int r = 0; r < 4; ++r) {
        int n = nb + ((lane >> 4) << 2) + r;
        if (n < N) x1g[(size_t)n * 64 + f * 16 + j] = leaky(acc[r] + bb);
    }
}

// ---------------------------------------------------------------------------
// Fused lin + gcn1-matmul + fused k_fill tail blocks (CSR fill atomics ride
// in the matmul blocks' shadow; fill needs offs/pos which scan_final wrote).
__global__ __launch_bounds__(256) void k_lin1(const float* __restrict__ x1,
                                              const float* __restrict__ Wl,
                                              const float* __restrict__ bl,
                                              const float* __restrict__ Wg1,
                                              const float* __restrict__ dinvv,
                                              const int* __restrict__ rowv,
                                              const int* __restrict__ colv,
                                              int* __restrict__ pos,
                                              int* __restrict__ csr, int E,
                                              unsigned short* __restrict__ z,
                                              int N, int NGB) {
    __shared__ float4 xt4[1024];
    __shared__ float4 wt4[1024];
    const int tid = threadIdx.x;
    const int bid = blockIdx.x;

    if (bid >= NGB) {  // ---- fused CSR fill ----
        int e = (bid - NGB) * 256 + tid;
        if (e < E) {
            int p = atomicAdd(&pos[colv[e]], 1);
            csr[p] = rowv[e];
        }
        return;
    }

    const int n0 = bid * 64;
    const int nq = tid & 15;
    const int jq = tid >> 4;

#pragma unroll
    for (int v = 0; v < 4; ++v) {
        int L = v * 256 + tid;
        int n = L >> 4, c4 = L & 15;
        int nn = n0 + n; if (nn >= N) nn = N - 1;
        xt4[n * 16 + (c4 ^ (n & 15))] = *reinterpret_cast<const float4*>(x1 + (size_t)nn * 64 + c4 * 4);
        wt4[L] = *reinterpret_cast<const float4*>(Wl + (size_t)L * 4);
    }
    __syncthreads();

    float4 acc[4];
#pragma unroll
    for (int g = 0; g < 4; ++g) acc[g] = make_float4(0.f, 0.f, 0.f, 0.f);
    for (int k = 0; k < 64; k += 4) {
        float4 w0 = wt4[(k + 0) * 16 + jq];
        float4 w1 = wt4[(k + 1) * 16 + jq];
        float4 w2 = wt4[(k + 2) * 16 + jq];
        float4 w3 = wt4[(k + 3) * 16 + jq];
        int k4 = k >> 2;
#pragma unroll
        for (int g = 0; g < 4; ++g) {
            int n = nq + (g << 4);
            float4 xv = xt4[n * 16 + (k4 ^ (n & 15))];
            fma4(acc[g], xv.x, w0);
            fma4(acc[g], xv.y, w1);
            fma4(acc[g], xv.z, w2);
            fma4(acc[g], xv.w, w3);
        }
    }
    float4 bb = *reinterpret_cast<const float4*>(bl + jq * 4);
    __syncthreads();

#pragma unroll
    for (int g = 0; g < 4; ++g) {
        int n = nq + (g << 4);
        float4 h;
        h.x = leaky(acc[g].x + bb.x);
        h.y = leaky(acc[g].y + bb.y);
        h.z = leaky(acc[g].z + bb.z);
        h.w = leaky(acc[g].w + bb.w);
        xt4[n * 16 + (jq ^ (n & 15))] = h;
    }
#pragma unroll
    for (int v = 0; v < 4; ++v) {
        int L = v * 256 + tid;
        wt4[L] = *reinterpret_cast<const float4*>(Wg1 + (size_t)L * 4);
    }
    __syncthreads();

#pragma unroll
    for (int g = 0; g < 4; ++g) acc[g] = make_float4(0.f, 0.f, 0.f, 0.f);
    for (int k = 0; k < 64; k += 4) {
        float4 w0 = wt4[(k + 0) * 16 + jq];
        float4 w1 = wt4[(k + 1) * 16 + jq];
        float4 w2 = wt4[(k + 2) * 16 + jq];
        float4 w3 = wt4[(k + 3) * 16 + jq];
        int k4 = k >> 2;
#pragma unroll
        for (int g = 0; g < 4; ++g) {
            int n = nq + (g << 4);
            float4 xv = xt4[n * 16 + (k4 ^ (n & 15))];
            fma4(acc[g], xv.x, w0);
            fma4(acc[g], xv.y, w1);
            fma4(acc[g], xv.z, w2);
            fma4(acc[g], xv.w, w3);
        }
    }
#pragma unroll
    for (int g = 0; g < 4; ++g) {
        int n = nq + (g << 4);
        if (n0 + n >= N) continue;
        float dv = dinvv[n0 + n];
        ushort4 o;
        o.x = f2bf(acc[g].x * dv); o.y = f2bf(acc[g].y * dv);
        o.z = f2bf(acc[g].z * dv); o.w = f2bf(acc[g].w * dv);
        *reinterpret_cast<ushort4*>(z + (size_t)(n0 + n) * 64 + jq * 4) = o;
    }
}

// ---------------------------------------------------------------------------
// Generic 64x64 node-matmul (layers 2,3; unchanged)
__global__ __launch_bounds__(256, 4) void k_mm64(const float* __restrict__ xin,
                                                 const float* __restrict__ W,
                                                 const float* __restrict__ dinvv,
                                                 unsigned short* __restrict__ z, int N) {
    __shared__ float4 xt4[1024];
    __shared__ float4 wt4[1024];
    const int tid = threadIdx.x;
    const int n0 = blockIdx.x * 64;
#pragma unroll
    for (int v = 0; v < 4; ++v) {
        int L = v * 256 + tid;
        int n = L >> 4, c4 = L & 15;
        int nn = n0 + n; if (nn >= N) nn = N - 1;
        xt4[n * 16 + (c4 ^ (n & 15))] = *reinterpret_cast<const float4*>(xin + (size_t)nn * 64 + c4 * 4);
        wt4[L] = *reinterpret_cast<const float4*>(W + (size_t)L * 4);
    }
    __syncthreads();
    const int nq = tid & 15;
    const int jq = tid >> 4;
    float4 acc[4];
#pragma unroll
    for (int g = 0; g < 4; ++g) acc[g] = make_float4(0.f, 0.f, 0.f, 0.f);
    for (int k = 0; k < 64; k += 4) {
        float4 w0 = wt4[(k + 0) * 16 + jq];
        float4 w1 = wt4[(k + 1) * 16 + jq];
        float4 w2 = wt4[(k + 2) * 16 + jq];
        float4 w3 = wt4[(k + 3) * 16 + jq];
        int k4 = k >> 2;
#pragma unroll
        for (int g = 0; g < 4; ++g) {
            int n = nq + (g << 4);
            float4 xv = xt4[n * 16 + (k4 ^ (n & 15))];
            fma4(acc[g], xv.x, w0);
            fma4(acc[g], xv.y, w1);
            fma4(acc[g], xv.z, w2);
            fma4(acc[g], xv.w, w3);
        }
    }
#pragma unroll
    for (int g = 0; g < 4; ++g) {
        int n = nq + (g << 4);
        if (n0 + n >= N) continue;
        float dv = dinvv[n0 + n];
        ushort4 o;
        o.x = f2bf(acc[g].x * dv); o.y = f2bf(acc[g].y * dv);
        o.z = f2bf(acc[g].z * dv); o.w = f2bf(acc[g].w * dv);
        *reinterpret_cast<ushort4*>(z + (size_t)(n0 + n) * 64 + jq * 4) = o;
    }
}

// ---------------------------------------------------------------------------
// Gather aggregation v2 (R9 best): paired-edge dword gathers, scalar CSR path.
__global__ __launch_bounds__(256) void k_agg(const unsigned short* __restrict__ z,
                                             const int* __restrict__ offs,
                                             const int* __restrict__ csr,
                                             const float* __restrict__ dinv,
                                             const float* __restrict__ bias,
                                             const float* __restrict__ x1,
                                             float* __restrict__ xout, int N) {
    int lane = threadIdx.x & 63;
    int c = blockIdx.x * 4 + (threadIdx.x >> 6);
    if (c >= N) return;
    int s = __builtin_amdgcn_readfirstlane(offs[c]);
    int e = __builtin_amdgcn_readfirstlane(offs[c + 1]);
    const int half = lane >> 5;
    const int d = lane & 31;
    const unsigned* __restrict__ zr = (const unsigned*)z;  // 32 dwords / row

    float ax = 0.f, ay = 0.f;
    if (half == 0) {  // self-loop once
        unsigned sv = zr[(size_t)c * 32 + d];
        ax = bf2f((unsigned short)(sv & 0xffffu));
        ay = bf2f((unsigned short)(sv >> 16));
    }
    float ux[8] = {0, 0, 0, 0, 0, 0, 0, 0};
    float uy[8] = {0, 0, 0, 0, 0, 0, 0, 0};
    int j = s;
    for (; j + 16 <= e; j += 16) {
#pragma unroll
        for (int u = 0; u < 8; ++u) {
            int r0 = csr[j + 2 * u];
            int r1 = csr[j + 2 * u + 1];
            int r = half ? r1 : r0;
            unsigned v = zr[(size_t)r * 32 + d];
            ux[u] += bf2f((unsigned short)(v & 0xffffu));
            uy[u] += bf2f((unsigned short)(v >> 16));
        }
    }
    for (; j + 2 <= e; j += 2) {
        int r0 = csr[j];
        int r1 = csr[j + 1];
        int r = half ? r1 : r0;
        unsigned v = zr[(size_t)r * 32 + d];
        ax += bf2f((unsigned short)(v & 0xffffu));
        ay += bf2f((unsigned short)(v >> 16));
    }
    if (j < e && half == 0) {  // odd leftover
        int r = csr[j];
        unsigned v = zr[(size_t)r * 32 + d];
        ax += bf2f((unsigned short)(v & 0xffffu));
        ay += bf2f((unsigned short)(v >> 16));
    }
    float tx = ax + ((ux[0] + ux[1]) + (ux[2] + ux[3])) + ((ux[4] + ux[5]) + (ux[6] + ux[7]));
    float ty = ay + ((uy[0] + uy[1]) + (uy[2] + uy[3])) + ((uy[4] + uy[5]) + (uy[6] + uy[7]));
    tx += __shfl_xor(tx, 32);
    ty += __shfl_xor(ty, 32);
    if (half == 0) {
        float dv = dinv[c];
        float2 bb = reinterpret_cast<const float2*>(bias)[d];
        float2 xx = *reinterpret_cast<const float2*>(x1 + (size_t)c * 64 + 2 * d);
        float2 o;
        o.x = dv * tx + bb.x + xx.x;
        o.y = dv * ty + bb.y + xx.y;
        *reinterpret_cast<float2*>(xout + (size_t)c * 64 + 2 * d) = o;
    }
}

// ---------------------------------------------------------------------------
// head (unchanged)
__global__ __launch_bounds__(256) void k_head(const float* __restrict__ xin,
                                              const float* __restrict__ Wo1,
                                              const float* __restrict__ bo1,
                                              const float* __restrict__ Wo2,
                                              const float* __restrict__ bo2,
                                              float* __restrict__ out, int N) {
    __shared__ float xsg[64][65];
    __shared__ float wg[64][65];
    __shared__ float hs[64][65];
    __shared__ float wo2[128];
    const int tid = threadIdx.x;
    const int n0 = blockIdx.x * 64;
#pragma unroll
    for (int v = 0; v < 4; ++v) {
        int idx = tid + v * 256;
        int n = idx >> 4;
        int jj = (idx & 15) << 2;
        float4 xv = make_float4(0.f, 0.f, 0.f, 0.f);
        if (n0 + n < N) xv = *reinterpret_cast<const float4*>(xin + (size_t)(n0 + n) * 64 + jj);
        xsg[n][jj] = xv.x; xsg[n][jj + 1] = xv.y; xsg[n][jj + 2] = xv.z; xsg[n][jj + 3] = xv.w;
        float4 w = *reinterpret_cast<const float4*>(Wo1 + (size_t)n * 64 + jj);
        wg[n][jj] = w.x; wg[n][jj + 1] = w.y; wg[n][jj + 2] = w.z; wg[n][jj + 3] = w.w;
    }
    if (tid < 128) wo2[tid] = Wo2[tid];
    __syncthreads();
    int j = tid & 63;
    int g = tid >> 6;
    float bj = bo1[j];
    for (int i = 0; i < 16; ++i) {
        int n = g * 16 + i;
        float a = bj;
#pragma unroll
        for (int k = 0; k < 64; ++k) a += xsg[n][k] * wg[k][j];
        hs[n][j] = leaky(a);
    }
    __syncthreads();
    if (tid < 128) {
        int n = tid >> 1;
        int j2 = tid & 1;
        float a = bo2[j2];
#pragma unroll
        for (int k = 0; k < 64; ++k) a += hs[n][k] * wo2[k * 2 + j2];
        if (n0 + n < N) out[(size_t)(n0 + n) * 2 + j2] = 1.f / (1.f + expf(-a));
    }
}

// ---------------------------------------------------------------------------
extern "C" void kernel_launch(void* const* d_in, const int* in_sizes, int n_in,
                              void* d_out, int out_size, void* d_ws, size_t ws_size,
                              hipStream_t stream) {
    const float* screen   = (const float*)d_in[0];
    const float* des      = (const float*)d_in[1];
    const float* tweet    = (const float*)d_in[2];
    const float* profile  = (const float*)d_in[3];
    const float* personal = (const float*)d_in[4];
    const int*   edge     = (const int*)d_in[5];
    const float* Ws  = (const float*)d_in[6],  *bs  = (const float*)d_in[7];
    const float* Wd  = (const float*)d_in[8],  *bd  = (const float*)d_in[9];
    const float* Wt  = (const float*)d_in[10], *bt  = (const float*)d_in[11];
    const float* Wp  = (const float*)d_in[12], *bp  = (const float*)d_in[13];
    const float* Wpe = (const float*)d_in[14], *bpe = (const float*)d_in[15];
    const float* Wl  = (const float*)d_in[16], *bl  = (const float*)d_in[17];
    const float* Wg1 = (const float*)d_in[18], *bg1 = (const float*)d_in[19];
    const float* Wg2 = (const float*)d_in[20], *bg2 = (const float*)d_in[21];
    const float* Wg3 = (const float*)d_in[22], *bg3 = (const float*)d_in[23];
    const float* Wo1 = (const float*)d_in[24], *bo1 = (const float*)d_in[25];
    const float* Wo2 = (const float*)d_in[26], *bo2 = (const float*)d_in[27];

    const int N = in_sizes[0] / 768;   // 50000
    const int E = in_sizes[5] / 2;     // 1600000
    const int* row = edge;
    const int* col = edge + E;

    size_t off = 0;
    auto alloc = [&](size_t bytes) -> void* {
        void* p = (char*)d_ws + off;
        off += (bytes + 255) & ~(size_t)255;
        return p;
    };
    const size_t NF = (size_t)N * 64;
    float* x1   = (float*)alloc(NF * 4);
    float* xa   = (float*)alloc(NF * 4);
    float* xb   = (float*)alloc(NF * 4);
    unsigned short* z = (unsigned short*)alloc(NF * 2);
    float* dinv = (float*)alloc((size_t)N * 4);
    int* deg  = (int*)alloc((size_t)N * 4);
    int* part = (int*)alloc((size_t)N * 4);
    int* offs = (int*)alloc((size_t)(N + 1) * 4);
    int* pos  = (int*)alloc((size_t)N * 4);
    int* csr  = (int*)alloc((size_t)E * 4);
    const int NB = (N + 255) / 256;
    int* bsum = (int*)alloc((size_t)NB * 4);
    int* boff = (int*)alloc((size_t)NB * 4);
    (void)ws_size; (void)n_in; (void)out_size;

    hipMemsetAsync(deg, 0, (size_t)N * 4, stream);

    // Phase A: MFMA feature linears + tiny linears + degree count (fused grid)
    const int NG = (N + 127) / 128;
    const int NSM = (N + 511) / 512;
    const int NDEG = (E + 511) / 512;
    k_featB<<<NG * 3 + NSM + NDEG, 512, 0, stream>>>(screen, des, tweet,
                                                     Ws, bs, Wd, bd, Wt, bt,
                                                     profile, personal, Wp, bp, Wpe, bpe,
                                                     col, deg, E,
                                                     x1, N, NG, NSM);

    // degree scan -> offs, pos, dinv
    k_scan_part<<<NB, 256, 0, stream>>>(deg, part, bsum, N);
    k_scan_sums<<<1, 256, 0, stream>>>(bsum, boff, NB, offs + N);
    k_scan_final<<<NB, 256, 0, stream>>>(part, boff, deg, offs, pos, dinv, N);

    const int NGB = (N + 63) / 64;
    const int NFILL = (E + 255) / 256;
    const int NAB = (N + 3) / 4;
    // layer 1 lin+matmul fused, with CSR fill as tail blocks
    k_lin1<<<NGB + NFILL, 256, 0, stream>>>(x1, Wl, bl, Wg1, dinv,
                                            row, col, pos, csr, E, z, N, NGB);
    k_agg<<<NAB, 256, 0, stream>>>(z, offs, csr, dinv, bg1, x1, xb, N);
    // layer 2
    k_mm64<<<NGB, 256, 0, stream>>>(xb, Wg2, dinv, z, N);
    k_agg<<<NAB, 256, 0, stream>>>(z, offs, csr, dinv, bg2, x1, xa, N);
    // layer 3
    k_mm64<<<NGB, 256, 0, stream>>>(xa, Wg3, dinv, z, N);
    k_agg<<<NAB, 256, 0, stream>>>(z, offs, csr, dinv, bg3, x1, xb, N);

    // head
    k_head<<<NGB, 256, 0, stream>>>(xb, Wo1, bo1, Wo2, bo2, (float*)d_out, N);
}

// Round 12
// 467.473 us; speedup vs baseline: 1.1346x; 1.0167x over previous
//
#include <hip/hip_runtime.h>

__device__ __forceinline__ float leaky(float v) { return v >= 0.f ? v : 0.01f * v; }

__device__ __forceinline__ void fma4(float4& a, float s, const float4& w) {
    a.x = fmaf(s, w.x, a.x); a.y = fmaf(s, w.y, a.y);
    a.z = fmaf(s, w.z, a.z); a.w = fmaf(s, w.w, a.w);
}

__device__ __forceinline__ unsigned short f2bf(float x) {  // RNE
    unsigned b = __float_as_uint(x);
    return (unsigned short)((b + 0x7FFFu + ((b >> 16) & 1u)) >> 16);
}
__device__ __forceinline__ float bf2f(unsigned short u) {
    return __uint_as_float(((unsigned)u) << 16);
}

typedef __attribute__((ext_vector_type(8))) short short8v;
typedef __attribute__((ext_vector_type(4))) float float4v;

// ---------------------------------------------------------------------------
// Scan kernels (unchanged)
__global__ __launch_bounds__(256) void k_scan_part(const int* __restrict__ deg,
                                                   int* __restrict__ part,
                                                   int* __restrict__ bsum, int N) {
    __shared__ int tmp[256];
    int tid = threadIdx.x;
    int i = blockIdx.x * 256 + tid;
    int v = (i < N) ? deg[i] : 0;
    tmp[tid] = v;
    __syncthreads();
    for (int ofs = 1; ofs < 256; ofs <<= 1) {
        int t = (tid >= ofs) ? tmp[tid - ofs] : 0;
        __syncthreads();
        tmp[tid] += t;
        __syncthreads();
    }
    int incl = tmp[tid];
    if (i < N) part[i] = incl - v;
    if (tid == 255) bsum[blockIdx.x] = incl;
}

__global__ __launch_bounds__(256) void k_scan_sums(const int* __restrict__ bsum,
                                                   int* __restrict__ boff, int NB,
                                                   int* __restrict__ offs_last) {
    __shared__ int tmp[256];
    int tid = threadIdx.x;
    int v = (tid < NB) ? bsum[tid] : 0;
    tmp[tid] = v;
    __syncthreads();
    for (int ofs = 1; ofs < 256; ofs <<= 1) {
        int t = (tid >= ofs) ? tmp[tid - ofs] : 0;
        __syncthreads();
        tmp[tid] += t;
        __syncthreads();
    }
    int incl = tmp[tid];
    if (tid < NB) boff[tid] = incl - v;
    if (tid == 255) offs_last[0] = incl;
}

__global__ __launch_bounds__(256) void k_scan_final(const int* __restrict__ part,
                                                    const int* __restrict__ boff,
                                                    const int* __restrict__ deg,
                                                    int* __restrict__ offs,
                                                    int* __restrict__ pos,
                                                    float* __restrict__ dinv, int N) {
    int i = blockIdx.x * 256 + threadIdx.x;
    if (i < N) {
        int o = part[i] + boff[blockIdx.x];
        offs[i] = o;
        pos[i] = o;
        dinv[i] = rsqrtf((float)(deg[i] + 1));
    }
}

// ---------------------------------------------------------------------------
// Phase A — MFMA featB + tiny linears, with the degree-count atomics inlined
// into EVERY block's prologue (fire-and-forget; they overlap the stalled
// feature loads instead of running as serialized tail blocks like R11).
// sched_barrier(0) per K-iteration pins the 4-deep prefetch ring.
__global__ __launch_bounds__(512) void k_featB(
    const float* __restrict__ s, const float* __restrict__ d, const float* __restrict__ t,
    const float* __restrict__ Ws, const float* __restrict__ bs2,
    const float* __restrict__ Wd, const float* __restrict__ bd2,
    const float* __restrict__ Wt, const float* __restrict__ bt2,
    const float* __restrict__ prof, const float* __restrict__ pers,
    const float* __restrict__ Wp, const float* __restrict__ bp,
    const float* __restrict__ Wpe, const float* __restrict__ bpe,
    const int* __restrict__ colv, int* __restrict__ deg, int E,
    float* __restrict__ x1g, int N, int NG, int NSM) {
    __shared__ short8v wfv[3072];  // [hi:1536][lo:1536] fragments, 48 KB

    const int bid = blockIdx.x;
    const int tid = threadIdx.x;

    // ---- fused degree atomics (all blocks), fire-and-forget ----
    {
        const int NW = 3 * NG + NSM;
        int eper = (E + NW - 1) / NW;
        int ebase = bid * eper;
        int eend = ebase + eper; if (eend > E) eend = E;
        for (int e = ebase + tid; e < eend; e += 512)
            atomicAdd(&deg[colv[e]], 1);
    }

    if (bid >= 3 * NG) {  // ---- fused tiny linears ----
        int n = (bid - 3 * NG) * 512 + tid;
        if (n >= N) return;
        float pv[5], pe[7];
#pragma unroll
        for (int i = 0; i < 5; ++i) pv[i] = prof[(size_t)n * 5 + i];
#pragma unroll
        for (int i = 0; i < 7; ++i) pe[i] = pers[(size_t)n * 7 + i];
        float o[16];
#pragma unroll
        for (int j = 0; j < 8; ++j) {
            float a = bp[j];
#pragma unroll
            for (int i = 0; i < 5; ++i) a = fmaf(pv[i], Wp[i * 8 + j], a);
            o[j] = leaky(a);
            float a2 = bpe[j];
#pragma unroll
            for (int i = 0; i < 7; ++i) a2 = fmaf(pe[i], Wpe[i * 8 + j], a2);
            o[8 + j] = leaky(a2);
        }
#pragma unroll
        for (int v = 0; v < 4; ++v)
            *reinterpret_cast<float4*>(x1g + (size_t)n * 64 + 48 + v * 4) =
                make_float4(o[v * 4], o[v * 4 + 1], o[v * 4 + 2], o[v * 4 + 3]);
        return;
    }

    const int f = bid / NG;
    const int grp = bid - f * NG;
    const float* __restrict__ X = (f == 0) ? s : ((f == 1) ? d : t);
    const float* __restrict__ W = (f == 0) ? Ws : ((f == 1) ? Wd : Wt);
    const float* __restrict__ B = (f == 0) ? bs2 : ((f == 1) ? bd2 : bt2);
    const int n0 = grp * 128;
    const int lane = tid & 63;
    const int wid = tid >> 6;  // 0..7

    short* wfs = (short*)wfv;
#pragma unroll
    for (int v = 0; v < 6; ++v) {
        int idx4 = tid + v * 512;          // 3072 float4 = 768x16
        float4 w4 = *reinterpret_cast<const float4*>(W + (size_t)idx4 * 4);
        int k = idx4 >> 2;
        int j0 = (idx4 & 3) * 4;
        int c = k >> 5, g = (k >> 3) & 3, i = k & 7;
        float wq[4] = {w4.x, w4.y, w4.z, w4.w};
#pragma unroll
        for (int q = 0; q < 4; ++q) {
            int sl = (c * 64 + g * 16 + j0 + q) * 8 + i;
            unsigned short h = f2bf(wq[q]);
            wfs[sl] = (short)h;
            wfs[12288 + sl] = (short)f2bf(wq[q] - bf2f(h));
        }
    }
    __syncthreads();

    const int nb = n0 + wid * 16;
    int mrow = nb + (lane & 15); if (mrow >= N) mrow = N - 1;
    const float* base = X + (size_t)mrow * 768 + ((lane >> 4) << 3);

    float4 pa[4], pb[4];
#pragma unroll
    for (int u = 0; u < 4; ++u) {
        pa[u] = *reinterpret_cast<const float4*>(base + u * 32);
        pb[u] = *reinterpret_cast<const float4*>(base + u * 32 + 4);
    }
    __builtin_amdgcn_sched_barrier(0);  // ring loads issued before loop
    float4v acc = {0.f, 0.f, 0.f, 0.f};

#pragma unroll
    for (int c = 0; c < 24; ++c) {
        const int u = c & 3;
        float xs[8] = {pa[u].x, pa[u].y, pa[u].z, pa[u].w,
                       pb[u].x, pb[u].y, pb[u].z, pb[u].w};
        if (c + 4 < 24) {
            pa[u] = *reinterpret_cast<const float4*>(base + (c + 4) * 32);
            pb[u] = *reinterpret_cast<const float4*>(base + (c + 4) * 32 + 4);
        }
        short8v xh, xl;
#pragma unroll
        for (int i = 0; i < 8; ++i) {
            unsigned short h = f2bf(xs[i]);
            xh[i] = (short)h;
            xl[i] = (short)f2bf(xs[i] - bf2f(h));
        }
        short8v wh = wfv[c * 64 + lane];
        short8v wl = wfv[1536 + c * 64 + lane];
        acc = __builtin_amdgcn_mfma_f32_16x16x32_bf16(xh, wh, acc, 0, 0, 0);
        acc = __builtin_amdgcn_mfma_f32_16x16x32_bf16(xl, wh, acc, 0, 0, 0);
        acc = __builtin_amdgcn_mfma_f32_16x16x32_bf16(xh, wl, acc, 0, 0, 0);
        __builtin_amdgcn_sched_barrier(0);  // pin refill into THIS iteration
    }

    int j = lane & 15;
    float bb = B[j];
#pragma unroll
    for (int r = 0; r < 4; ++r) {
        int n = nb + ((lane >> 4) << 2) + r;
        if (n < N) x1g[(size_t)n * 64 + f * 16 + j] = leaky(acc[r] + bb);
    }
}

// ---------------------------------------------------------------------------
// Fused lin + gcn1-matmul, with CSR fill inlined into every block's prologue
// (3-phase batched: 8 col/row loads -> 8 returning atomics -> 8 scatter
// stores; ~3 round-trips, overlapped with the LDS staging below).
__global__ __launch_bounds__(256) void k_lin1(const float* __restrict__ x1,
                                              const float* __restrict__ Wl,
                                              const float* __restrict__ bl,
                                              const float* __restrict__ Wg1,
                                              const float* __restrict__ dinvv,
                                              const int* __restrict__ rowv,
                                              const int* __restrict__ colv,
                                              int* __restrict__ pos,
                                              int* __restrict__ csr, int E,
                                              unsigned short* __restrict__ z,
                                              int N, int NGB) {
    __shared__ float4 xt4[1024];
    __shared__ float4 wt4[1024];
    const int tid = threadIdx.x;
    const int bid = blockIdx.x;

    // ---- fused CSR fill prologue ----
    {
        int eper = (E + NGB - 1) / NGB;           // ~2046 -> 8 per thread
        int ebase = bid * eper;
        int eend = ebase + eper; if (eend > E) eend = E;
        int cols[8], rows[8];
#pragma unroll
        for (int r = 0; r < 8; ++r) {
            int e = ebase + tid + r * 256;
            cols[r] = (e < eend) ? colv[e] : -1;
            rows[r] = (e < eend) ? rowv[e] : 0;
        }
        int ps[8];
#pragma unroll
        for (int r = 0; r < 8; ++r)
            if (cols[r] >= 0) ps[r] = atomicAdd(&pos[cols[r]], 1);
#pragma unroll
        for (int r = 0; r < 8; ++r)
            if (cols[r] >= 0) csr[ps[r]] = rows[r];
    }

    const int n0 = bid * 64;
    const int nq = tid & 15;
    const int jq = tid >> 4;

#pragma unroll
    for (int v = 0; v < 4; ++v) {
        int L = v * 256 + tid;
        int n = L >> 4, c4 = L & 15;
        int nn = n0 + n; if (nn >= N) nn = N - 1;
        xt4[n * 16 + (c4 ^ (n & 15))] = *reinterpret_cast<const float4*>(x1 + (size_t)nn * 64 + c4 * 4);
        wt4[L] = *reinterpret_cast<const float4*>(Wl + (size_t)L * 4);
    }
    __syncthreads();

    float4 acc[4];
#pragma unroll
    for (int g = 0; g < 4; ++g) acc[g] = make_float4(0.f, 0.f, 0.f, 0.f);
    for (int k = 0; k < 64; k += 4) {
        float4 w0 = wt4[(k + 0) * 16 + jq];
        float4 w1 = wt4[(k + 1) * 16 + jq];
        float4 w2 = wt4[(k + 2) * 16 + jq];
        float4 w3 = wt4[(k + 3) * 16 + jq];
        int k4 = k >> 2;
#pragma unroll
        for (int g = 0; g < 4; ++g) {
            int n = nq + (g << 4);
            float4 xv = xt4[n * 16 + (k4 ^ (n & 15))];
            fma4(acc[g], xv.x, w0);
            fma4(acc[g], xv.y, w1);
            fma4(acc[g], xv.z, w2);
            fma4(acc[g], xv.w, w3);
        }
    }
    float4 bb = *reinterpret_cast<const float4*>(bl + jq * 4);
    __syncthreads();

#pragma unroll
    for (int g = 0; g < 4; ++g) {
        int n = nq + (g << 4);
        float4 h;
        h.x = leaky(acc[g].x + bb.x);
        h.y = leaky(acc[g].y + bb.y);
        h.z = leaky(acc[g].z + bb.z);
        h.w = leaky(acc[g].w + bb.w);
        xt4[n * 16 + (jq ^ (n & 15))] = h;
    }
#pragma unroll
    for (int v = 0; v < 4; ++v) {
        int L = v * 256 + tid;
        wt4[L] = *reinterpret_cast<const float4*>(Wg1 + (size_t)L * 4);
    }
    __syncthreads();

#pragma unroll
    for (int g = 0; g < 4; ++g) acc[g] = make_float4(0.f, 0.f, 0.f, 0.f);
    for (int k = 0; k < 64; k += 4) {
        float4 w0 = wt4[(k + 0) * 16 + jq];
        float4 w1 = wt4[(k + 1) * 16 + jq];
        float4 w2 = wt4[(k + 2) * 16 + jq];
        float4 w3 = wt4[(k + 3) * 16 + jq];
        int k4 = k >> 2;
#pragma unroll
        for (int g = 0; g < 4; ++g) {
            int n = nq + (g << 4);
            float4 xv = xt4[n * 16 + (k4 ^ (n & 15))];
            fma4(acc[g], xv.x, w0);
            fma4(acc[g], xv.y, w1);
            fma4(acc[g], xv.z, w2);
            fma4(acc[g], xv.w, w3);
        }
    }
#pragma unroll
    for (int g = 0; g < 4; ++g) {
        int n = nq + (g << 4);
        if (n0 + n >= N) continue;
        float dv = dinvv[n0 + n];
        ushort4 o;
        o.x = f2bf(acc[g].x * dv); o.y = f2bf(acc[g].y * dv);
        o.z = f2bf(acc[g].z * dv); o.w = f2bf(acc[g].w * dv);
        *reinterpret_cast<ushort4*>(z + (size_t)(n0 + n) * 64 + jq * 4) = o;
    }
}

// ---------------------------------------------------------------------------
// Generic 64x64 node-matmul (layers 2,3; unchanged)
__global__ __launch_bounds__(256, 4) void k_mm64(const float* __restrict__ xin,
                                                 const float* __restrict__ W,
                                                 const float* __restrict__ dinvv,
                                                 unsigned short* __restrict__ z, int N) {
    __shared__ float4 xt4[1024];
    __shared__ float4 wt4[1024];
    const int tid = threadIdx.x;
    const int n0 = blockIdx.x * 64;
#pragma unroll
    for (int v = 0; v < 4; ++v) {
        int L = v * 256 + tid;
        int n = L >> 4, c4 = L & 15;
        int nn = n0 + n; if (nn >= N) nn = N - 1;
        xt4[n * 16 + (c4 ^ (n & 15))] = *reinterpret_cast<const float4*>(xin + (size_t)nn * 64 + c4 * 4);
        wt4[L] = *reinterpret_cast<const float4*>(W + (size_t)L * 4);
    }
    __syncthreads();
    const int nq = tid & 15;
    const int jq = tid >> 4;
    float4 acc[4];
#pragma unroll
    for (int g = 0; g < 4; ++g) acc[g] = make_float4(0.f, 0.f, 0.f, 0.f);
    for (int k = 0; k < 64; k += 4) {
        float4 w0 = wt4[(k + 0) * 16 + jq];
        float4 w1 = wt4[(k + 1) * 16 + jq];
        float4 w2 = wt4[(k + 2) * 16 + jq];
        float4 w3 = wt4[(k + 3) * 16 + jq];
        int k4 = k >> 2;
#pragma unroll
        for (int g = 0; g < 4; ++g) {
            int n = nq + (g << 4);
            float4 xv = xt4[n * 16 + (k4 ^ (n & 15))];
            fma4(acc[g], xv.x, w0);
            fma4(acc[g], xv.y, w1);
            fma4(acc[g], xv.z, w2);
            fma4(acc[g], xv.w, w3);
        }
    }
#pragma unroll
    for (int g = 0; g < 4; ++g) {
        int n = nq + (g << 4);
        if (n0 + n >= N) continue;
        float dv = dinvv[n0 + n];
        ushort4 o;
        o.x = f2bf(acc[g].x * dv); o.y = f2bf(acc[g].y * dv);
        o.z = f2bf(acc[g].z * dv); o.w = f2bf(acc[g].w * dv);
        *reinterpret_cast<ushort4*>(z + (size_t)(n0 + n) * 64 + jq * 4) = o;
    }
}

// ---------------------------------------------------------------------------
// Gather aggregation v2 (unchanged): paired-edge dword gathers, scalar CSR.
__global__ __launch_bounds__(256) void k_agg(const unsigned short* __restrict__ z,
                                             const int* __restrict__ offs,
                                             const int* __restrict__ csr,
                                             const float* __restrict__ dinv,
                                             const float* __restrict__ bias,
                                             const float* __restrict__ x1,
                                             float* __restrict__ xout, int N) {
    int lane = threadIdx.x & 63;
    int c = blockIdx.x * 4 + (threadIdx.x >> 6);
    if (c >= N) return;
    int s = __builtin_amdgcn_readfirstlane(offs[c]);
    int e = __builtin_amdgcn_readfirstlane(offs[c + 1]);
    const int half = lane >> 5;
    const int d = lane & 31;
    const unsigned* __restrict__ zr = (const unsigned*)z;  // 32 dwords / row

    float ax = 0.f, ay = 0.f;
    if (half == 0) {  // self-loop once
        unsigned sv = zr[(size_t)c * 32 + d];
        ax = bf2f((unsigned short)(sv & 0xffffu));
        ay = bf2f((unsigned short)(sv >> 16));
    }
    float ux[8] = {0, 0, 0, 0, 0, 0, 0, 0};
    float uy[8] = {0, 0, 0, 0, 0, 0, 0, 0};
    int j = s;
    for (; j + 16 <= e; j += 16) {
#pragma unroll
        for (int u = 0; u < 8; ++u) {
            int r0 = csr[j + 2 * u];
            int r1 = csr[j + 2 * u + 1];
            int r = half ? r1 : r0;
            unsigned v = zr[(size_t)r * 32 + d];
            ux[u] += bf2f((unsigned short)(v & 0xffffu));
            uy[u] += bf2f((unsigned short)(v >> 16));
        }
    }
    for (; j + 2 <= e; j += 2) {
        int r0 = csr[j];
        int r1 = csr[j + 1];
        int r = half ? r1 : r0;
        unsigned v = zr[(size_t)r * 32 + d];
        ax += bf2f((unsigned short)(v & 0xffffu));
        ay += bf2f((unsigned short)(v >> 16));
    }
    if (j < e && half == 0) {  // odd leftover
        int r = csr[j];
        unsigned v = zr[(size_t)r * 32 + d];
        ax += bf2f((unsigned short)(v & 0xffffu));
        ay += bf2f((unsigned short)(v >> 16));
    }
    float tx = ax + ((ux[0] + ux[1]) + (ux[2] + ux[3])) + ((ux[4] + ux[5]) + (ux[6] + ux[7]));
    float ty = ay + ((uy[0] + uy[1]) + (uy[2] + uy[3])) + ((uy[4] + uy[5]) + (uy[6] + uy[7]));
    tx += __shfl_xor(tx, 32);
    ty += __shfl_xor(ty, 32);
    if (half == 0) {
        float dv = dinv[c];
        float2 bb = reinterpret_cast<const float2*>(bias)[d];
        float2 xx = *reinterpret_cast<const float2*>(x1 + (size_t)c * 64 + 2 * d);
        float2 o;
        o.x = dv * tx + bb.x + xx.x;
        o.y = dv * ty + bb.y + xx.y;
        *reinterpret_cast<float2*>(xout + (size_t)c * 64 + 2 * d) = o;
    }
}

// ---------------------------------------------------------------------------
// head (unchanged)
__global__ __launch_bounds__(256) void k_head(const float* __restrict__ xin,
                                              const float* __restrict__ Wo1,
                                              const float* __restrict__ bo1,
                                              const float* __restrict__ Wo2,
                                              const float* __restrict__ bo2,
                                              float* __restrict__ out, int N) {
    __shared__ float xsg[64][65];
    __shared__ float wg[64][65];
    __shared__ float hs[64][65];
    __shared__ float wo2[128];
    const int tid = threadIdx.x;
    const int n0 = blockIdx.x * 64;
#pragma unroll
    for (int v = 0; v < 4; ++v) {
        int idx = tid + v * 256;
        int n = idx >> 4;
        int jj = (idx & 15) << 2;
        float4 xv = make_float4(0.f, 0.f, 0.f, 0.f);
        if (n0 + n < N) xv = *reinterpret_cast<const float4*>(xin + (size_t)(n0 + n) * 64 + jj);
        xsg[n][jj] = xv.x; xsg[n][jj + 1] = xv.y; xsg[n][jj + 2] = xv.z; xsg[n][jj + 3] = xv.w;
        float4 w = *reinterpret_cast<const float4*>(Wo1 + (size_t)n * 64 + jj);
        wg[n][jj] = w.x; wg[n][jj + 1] = w.y; wg[n][jj + 2] = w.z; wg[n][jj + 3] = w.w;
    }
    if (tid < 128) wo2[tid] = Wo2[tid];
    __syncthreads();
    int j = tid & 63;
    int g = tid >> 6;
    float bj = bo1[j];
    for (int i = 0; i < 16; ++i) {
        int n = g * 16 + i;
        float a = bj;
#pragma unroll
        for (int k = 0; k < 64; ++k) a += xsg[n][k] * wg[k][j];
        hs[n][j] = leaky(a);
    }
    __syncthreads();
    if (tid < 128) {
        int n = tid >> 1;
        int j2 = tid & 1;
        float a = bo2[j2];
#pragma unroll
        for (int k = 0; k < 64; ++k) a += hs[n][k] * wo2[k * 2 + j2];
        if (n0 + n < N) out[(size_t)(n0 + n) * 2 + j2] = 1.f / (1.f + expf(-a));
    }
}

// ---------------------------------------------------------------------------
extern "C" void kernel_launch(void* const* d_in, const int* in_sizes, int n_in,
                              void* d_out, int out_size, void* d_ws, size_t ws_size,
                              hipStream_t stream) {
    const float* screen   = (const float*)d_in[0];
    const float* des      = (const float*)d_in[1];
    const float* tweet    = (const float*)d_in[2];
    const float* profile  = (const float*)d_in[3];
    const float* personal = (const float*)d_in[4];
    const int*   edge     = (const int*)d_in[5];
    const float* Ws  = (const float*)d_in[6],  *bs  = (const float*)d_in[7];
    const float* Wd  = (const float*)d_in[8],  *bd  = (const float*)d_in[9];
    const float* Wt  = (const float*)d_in[10], *bt  = (const float*)d_in[11];
    const float* Wp  = (const float*)d_in[12], *bp  = (const float*)d_in[13];
    const float* Wpe = (const float*)d_in[14], *bpe = (const float*)d_in[15];
    const float* Wl  = (const float*)d_in[16], *bl  = (const float*)d_in[17];
    const float* Wg1 = (const float*)d_in[18], *bg1 = (const float*)d_in[19];
    const float* Wg2 = (const float*)d_in[20], *bg2 = (const float*)d_in[21];
    const float* Wg3 = (const float*)d_in[22], *bg3 = (const float*)d_in[23];
    const float* Wo1 = (const float*)d_in[24], *bo1 = (const float*)d_in[25];
    const float* Wo2 = (const float*)d_in[26], *bo2 = (const float*)d_in[27];

    const int N = in_sizes[0] / 768;   // 50000
    const int E = in_sizes[5] / 2;     // 1600000
    const int* row = edge;
    const int* col = edge + E;

    size_t off = 0;
    auto alloc = [&](size_t bytes) -> void* {
        void* p = (char*)d_ws + off;
        off += (bytes + 255) & ~(size_t)255;
        return p;
    };
    const size_t NF = (size_t)N * 64;
    float* x1   = (float*)alloc(NF * 4);
    float* xa   = (float*)alloc(NF * 4);
    float* xb   = (float*)alloc(NF * 4);
    unsigned short* z = (unsigned short*)alloc(NF * 2);
    float* dinv = (float*)alloc((size_t)N * 4);
    int* deg  = (int*)alloc((size_t)N * 4);
    int* part = (int*)alloc((size_t)N * 4);
    int* offs = (int*)alloc((size_t)(N + 1) * 4);
    int* pos  = (int*)alloc((size_t)N * 4);
    int* csr  = (int*)alloc((size_t)E * 4);
    const int NB = (N + 255) / 256;
    int* bsum = (int*)alloc((size_t)NB * 4);
    int* boff = (int*)alloc((size_t)NB * 4);
    (void)ws_size; (void)n_in; (void)out_size;

    hipMemsetAsync(deg, 0, (size_t)N * 4, stream);

    // Phase A: MFMA feature linears + tiny linears, deg atomics inlined
    const int NG = (N + 127) / 128;
    const int NSM = (N + 511) / 512;
    k_featB<<<NG * 3 + NSM, 512, 0, stream>>>(screen, des, tweet,
                                              Ws, bs, Wd, bd, Wt, bt,
                                              profile, personal, Wp, bp, Wpe, bpe,
                                              col, deg, E,
                                              x1, N, NG, NSM);

    // degree scan -> offs, pos, dinv
    k_scan_part<<<NB, 256, 0, stream>>>(deg, part, bsum, N);
    k_scan_sums<<<1, 256, 0, stream>>>(bsum, boff, NB, offs + N);
    k_scan_final<<<NB, 256, 0, stream>>>(part, boff, deg, offs, pos, dinv, N);

    const int NGB = (N + 63) / 64;
    const int NAB = (N + 3) / 4;
    // layer 1 lin+matmul fused, CSR fill inlined into the same blocks
    k_lin1<<<NGB, 256, 0, stream>>>(x1, Wl, bl, Wg1, dinv,
                                    row, col, pos, csr, E, z, N, NGB);
    k_agg<<<NAB, 256, 0, stream>>>(z, offs, csr, dinv, bg1, x1, xb, N);
    // layer 2
    k_mm64<<<NGB, 256, 0, stream>>>(xb, Wg2, dinv, z, N);
    k_agg<<<NAB, 256, 0, stream>>>(z, offs, csr, dinv, bg2, x1, xa, N);
    // layer 3
    k_mm64<<<NGB, 256, 0, stream>>>(xa, Wg3, dinv, z, N);
    k_agg<<<NAB, 256, 0, stream>>>(z, offs, csr, dinv, bg3, x1, xb, N);

    // head
    k_head<<<NGB, 256, 0, stream>>>(xb, Wo1, bo1, Wo2, bo2, (float*)d_out, N);
}

// Round 13
// 405.495 us; speedup vs baseline: 1.3081x; 1.1528x over previous
//
#include <hip/hip_runtime.h>

__device__ __forceinline__ float leaky(float v) { return v >= 0.f ? v : 0.01f * v; }

__device__ __forceinline__ void fma4(float4& a, float s, const float4& w) {
    a.x = fmaf(s, w.x, a.x); a.y = fmaf(s, w.y, a.y);
    a.z = fmaf(s, w.z, a.z); a.w = fmaf(s, w.w, a.w);
}

__device__ __forceinline__ unsigned short f2bf(float x) {  // RNE
    unsigned b = __float_as_uint(x);
    return (unsigned short)((b + 0x7FFFu + ((b >> 16) & 1u)) >> 16);
}
__device__ __forceinline__ float bf2f(unsigned short u) {
    return __uint_as_float(((unsigned)u) << 16);
}

typedef __attribute__((ext_vector_type(8))) short short8v;
typedef __attribute__((ext_vector_type(4))) float float4v;

// ---------------------------------------------------------------------------
// Scan kernels (unchanged)
__global__ __launch_bounds__(256) void k_scan_part(const int* __restrict__ deg,
                                                   int* __restrict__ part,
                                                   int* __restrict__ bsum, int N) {
    __shared__ int tmp[256];
    int tid = threadIdx.x;
    int i = blockIdx.x * 256 + tid;
    int v = (i < N) ? deg[i] : 0;
    tmp[tid] = v;
    __syncthreads();
    for (int ofs = 1; ofs < 256; ofs <<= 1) {
        int t = (tid >= ofs) ? tmp[tid - ofs] : 0;
        __syncthreads();
        tmp[tid] += t;
        __syncthreads();
    }
    int incl = tmp[tid];
    if (i < N) part[i] = incl - v;
    if (tid == 255) bsum[blockIdx.x] = incl;
}

__global__ __launch_bounds__(256) void k_scan_sums(const int* __restrict__ bsum,
                                                   int* __restrict__ boff, int NB,
                                                   int* __restrict__ offs_last) {
    __shared__ int tmp[256];
    int tid = threadIdx.x;
    int v = (tid < NB) ? bsum[tid] : 0;
    tmp[tid] = v;
    __syncthreads();
    for (int ofs = 1; ofs < 256; ofs <<= 1) {
        int t = (tid >= ofs) ? tmp[tid - ofs] : 0;
        __syncthreads();
        tmp[tid] += t;
        __syncthreads();
    }
    int incl = tmp[tid];
    if (tid < NB) boff[tid] = incl - v;
    if (tid == 255) offs_last[0] = incl;
}

__global__ __launch_bounds__(256) void k_scan_final(const int* __restrict__ part,
                                                    const int* __restrict__ boff,
                                                    const int* __restrict__ deg,
                                                    int* __restrict__ offs,
                                                    int* __restrict__ pos,
                                                    float* __restrict__ dinv, int N) {
    int i = blockIdx.x * 256 + threadIdx.x;
    if (i < N) {
        int o = part[i] + boff[blockIdx.x];
        offs[i] = o;
        pos[i] = o;
        dinv[i] = rsqrtf((float)(deg[i] + 1));
    }
}

// ---------------------------------------------------------------------------
// Phase A — MFMA featB + tiny linears + inlined degree atomics (unchanged R12).
__global__ __launch_bounds__(512) void k_featB(
    const float* __restrict__ s, const float* __restrict__ d, const float* __restrict__ t,
    const float* __restrict__ Ws, const float* __restrict__ bs2,
    const float* __restrict__ Wd, const float* __restrict__ bd2,
    const float* __restrict__ Wt, const float* __restrict__ bt2,
    const float* __restrict__ prof, const float* __restrict__ pers,
    const float* __restrict__ Wp, const float* __restrict__ bp,
    const float* __restrict__ Wpe, const float* __restrict__ bpe,
    const int* __restrict__ colv, int* __restrict__ deg, int E,
    float* __restrict__ x1g, int N, int NG, int NSM) {
    __shared__ short8v wfv[3072];  // [hi:1536][lo:1536] fragments, 48 KB

    const int bid = blockIdx.x;
    const int tid = threadIdx.x;

    {   // fused degree atomics (fire-and-forget)
        const int NW = 3 * NG + NSM;
        int eper = (E + NW - 1) / NW;
        int ebase = bid * eper;
        int eend = ebase + eper; if (eend > E) eend = E;
        for (int e = ebase + tid; e < eend; e += 512)
            atomicAdd(&deg[colv[e]], 1);
    }

    if (bid >= 3 * NG) {  // fused tiny linears
        int n = (bid - 3 * NG) * 512 + tid;
        if (n >= N) return;
        float pv[5], pe[7];
#pragma unroll
        for (int i = 0; i < 5; ++i) pv[i] = prof[(size_t)n * 5 + i];
#pragma unroll
        for (int i = 0; i < 7; ++i) pe[i] = pers[(size_t)n * 7 + i];
        float o[16];
#pragma unroll
        for (int j = 0; j < 8; ++j) {
            float a = bp[j];
#pragma unroll
            for (int i = 0; i < 5; ++i) a = fmaf(pv[i], Wp[i * 8 + j], a);
            o[j] = leaky(a);
            float a2 = bpe[j];
#pragma unroll
            for (int i = 0; i < 7; ++i) a2 = fmaf(pe[i], Wpe[i * 8 + j], a2);
            o[8 + j] = leaky(a2);
        }
#pragma unroll
        for (int v = 0; v < 4; ++v)
            *reinterpret_cast<float4*>(x1g + (size_t)n * 64 + 48 + v * 4) =
                make_float4(o[v * 4], o[v * 4 + 1], o[v * 4 + 2], o[v * 4 + 3]);
        return;
    }

    const int f = bid / NG;
    const int grp = bid - f * NG;
    const float* __restrict__ X = (f == 0) ? s : ((f == 1) ? d : t);
    const float* __restrict__ W = (f == 0) ? Ws : ((f == 1) ? Wd : Wt);
    const float* __restrict__ B = (f == 0) ? bs2 : ((f == 1) ? bd2 : bt2);
    const int n0 = grp * 128;
    const int lane = tid & 63;
    const int wid = tid >> 6;  // 0..7

    short* wfs = (short*)wfv;
#pragma unroll
    for (int v = 0; v < 6; ++v) {
        int idx4 = tid + v * 512;
        float4 w4 = *reinterpret_cast<const float4*>(W + (size_t)idx4 * 4);
        int k = idx4 >> 2;
        int j0 = (idx4 & 3) * 4;
        int c = k >> 5, g = (k >> 3) & 3, i = k & 7;
        float wq[4] = {w4.x, w4.y, w4.z, w4.w};
#pragma unroll
        for (int q = 0; q < 4; ++q) {
            int sl = (c * 64 + g * 16 + j0 + q) * 8 + i;
            unsigned short h = f2bf(wq[q]);
            wfs[sl] = (short)h;
            wfs[12288 + sl] = (short)f2bf(wq[q] - bf2f(h));
        }
    }
    __syncthreads();

    const int nb = n0 + wid * 16;
    int mrow = nb + (lane & 15); if (mrow >= N) mrow = N - 1;
    const float* base = X + (size_t)mrow * 768 + ((lane >> 4) << 3);

    float4 pa[4], pb[4];
#pragma unroll
    for (int u = 0; u < 4; ++u) {
        pa[u] = *reinterpret_cast<const float4*>(base + u * 32);
        pb[u] = *reinterpret_cast<const float4*>(base + u * 32 + 4);
    }
    __builtin_amdgcn_sched_barrier(0);
    float4v acc = {0.f, 0.f, 0.f, 0.f};

#pragma unroll
    for (int c = 0; c < 24; ++c) {
        const int u = c & 3;
        float xs[8] = {pa[u].x, pa[u].y, pa[u].z, pa[u].w,
                       pb[u].x, pb[u].y, pb[u].z, pb[u].w};
        if (c + 4 < 24) {
            pa[u] = *reinterpret_cast<const float4*>(base + (c + 4) * 32);
            pb[u] = *reinterpret_cast<const float4*>(base + (c + 4) * 32 + 4);
        }
        short8v xh, xl;
#pragma unroll
        for (int i = 0; i < 8; ++i) {
            unsigned short h = f2bf(xs[i]);
            xh[i] = (short)h;
            xl[i] = (short)f2bf(xs[i] - bf2f(h));
        }
        short8v wh = wfv[c * 64 + lane];
        short8v wl = wfv[1536 + c * 64 + lane];
        acc = __builtin_amdgcn_mfma_f32_16x16x32_bf16(xh, wh, acc, 0, 0, 0);
        acc = __builtin_amdgcn_mfma_f32_16x16x32_bf16(xl, wh, acc, 0, 0, 0);
        acc = __builtin_amdgcn_mfma_f32_16x16x32_bf16(xh, wl, acc, 0, 0, 0);
        __builtin_amdgcn_sched_barrier(0);
    }

    int j = lane & 15;
    float bb = B[j];
#pragma unroll
    for (int r = 0; r < 4; ++r) {
        int n = nb + ((lane >> 4) << 2) + r;
        if (n < N) x1g[(size_t)n * 64 + f * 16 + j] = leaky(acc[r] + bb);
    }
}

// ---------------------------------------------------------------------------
// Fused lin + gcn1-matmul + inlined CSR fill (unchanged R12). Writes z (bf16).
__global__ __launch_bounds__(256) void k_lin1(const float* __restrict__ x1,
                                              const float* __restrict__ Wl,
                                              const float* __restrict__ bl,
                                              const float* __restrict__ Wg1,
                                              const float* __restrict__ dinvv,
                                              const int* __restrict__ rowv,
                                              const int* __restrict__ colv,
                                              int* __restrict__ pos,
                                              int* __restrict__ csr, int E,
                                              unsigned short* __restrict__ z,
                                              int N, int NGB) {
    __shared__ float4 xt4[1024];
    __shared__ float4 wt4[1024];
    const int tid = threadIdx.x;
    const int bid = blockIdx.x;

    {   // fused CSR fill prologue
        int eper = (E + NGB - 1) / NGB;
        int ebase = bid * eper;
        int eend = ebase + eper; if (eend > E) eend = E;
        int cols[8], rows[8];
#pragma unroll
        for (int r = 0; r < 8; ++r) {
            int e = ebase + tid + r * 256;
            cols[r] = (e < eend) ? colv[e] : -1;
            rows[r] = (e < eend) ? rowv[e] : 0;
        }
        int ps[8];
#pragma unroll
        for (int r = 0; r < 8; ++r)
            if (cols[r] >= 0) ps[r] = atomicAdd(&pos[cols[r]], 1);
#pragma unroll
        for (int r = 0; r < 8; ++r)
            if (cols[r] >= 0) csr[ps[r]] = rows[r];
    }

    const int n0 = bid * 64;
    const int nq = tid & 15;
    const int jq = tid >> 4;

#pragma unroll
    for (int v = 0; v < 4; ++v) {
        int L = v * 256 + tid;
        int n = L >> 4, c4 = L & 15;
        int nn = n0 + n; if (nn >= N) nn = N - 1;
        xt4[n * 16 + (c4 ^ (n & 15))] = *reinterpret_cast<const float4*>(x1 + (size_t)nn * 64 + c4 * 4);
        wt4[L] = *reinterpret_cast<const float4*>(Wl + (size_t)L * 4);
    }
    __syncthreads();

    float4 acc[4];
#pragma unroll
    for (int g = 0; g < 4; ++g) acc[g] = make_float4(0.f, 0.f, 0.f, 0.f);
    for (int k = 0; k < 64; k += 4) {
        float4 w0 = wt4[(k + 0) * 16 + jq];
        float4 w1 = wt4[(k + 1) * 16 + jq];
        float4 w2 = wt4[(k + 2) * 16 + jq];
        float4 w3 = wt4[(k + 3) * 16 + jq];
        int k4 = k >> 2;
#pragma unroll
        for (int g = 0; g < 4; ++g) {
            int n = nq + (g << 4);
            float4 xv = xt4[n * 16 + (k4 ^ (n & 15))];
            fma4(acc[g], xv.x, w0);
            fma4(acc[g], xv.y, w1);
            fma4(acc[g], xv.z, w2);
            fma4(acc[g], xv.w, w3);
        }
    }
    float4 bb = *reinterpret_cast<const float4*>(bl + jq * 4);
    __syncthreads();

#pragma unroll
    for (int g = 0; g < 4; ++g) {
        int n = nq + (g << 4);
        float4 h;
        h.x = leaky(acc[g].x + bb.x);
        h.y = leaky(acc[g].y + bb.y);
        h.z = leaky(acc[g].z + bb.z);
        h.w = leaky(acc[g].w + bb.w);
        xt4[n * 16 + (jq ^ (n & 15))] = h;
    }
#pragma unroll
    for (int v = 0; v < 4; ++v) {
        int L = v * 256 + tid;
        wt4[L] = *reinterpret_cast<const float4*>(Wg1 + (size_t)L * 4);
    }
    __syncthreads();

#pragma unroll
    for (int g = 0; g < 4; ++g) acc[g] = make_float4(0.f, 0.f, 0.f, 0.f);
    for (int k = 0; k < 64; k += 4) {
        float4 w0 = wt4[(k + 0) * 16 + jq];
        float4 w1 = wt4[(k + 1) * 16 + jq];
        float4 w2 = wt4[(k + 2) * 16 + jq];
        float4 w3 = wt4[(k + 3) * 16 + jq];
        int k4 = k >> 2;
#pragma unroll
        for (int g = 0; g < 4; ++g) {
            int n = nq + (g << 4);
            float4 xv = xt4[n * 16 + (k4 ^ (n & 15))];
            fma4(acc[g], xv.x, w0);
            fma4(acc[g], xv.y, w1);
            fma4(acc[g], xv.z, w2);
            fma4(acc[g], xv.w, w3);
        }
    }
#pragma unroll
    for (int g = 0; g < 4; ++g) {
        int n = nq + (g << 4);
        if (n0 + n >= N) continue;
        float dv = dinvv[n0 + n];
        ushort4 o;
        o.x = f2bf(acc[g].x * dv); o.y = f2bf(acc[g].y * dv);
        o.z = f2bf(acc[g].z * dv); o.w = f2bf(acc[g].w * dv);
        *reinterpret_cast<ushort4*>(z + (size_t)(n0 + n) * 64 + jq * 4) = o;
    }
}

// ---------------------------------------------------------------------------
// Fused aggregate + next-layer matmul: per block 4 nodes (1/wave).
// Gather phase = proven v2 loop; x_next = dinv*acc + bias + x1 -> LDS;
// mm phase: z_next[c][j] = (x_next[c] @ Wn)[j] * dinv[c], bf16 out.
__global__ __launch_bounds__(256) void k_aggmm(const unsigned short* __restrict__ z,
                                               const int* __restrict__ offs,
                                               const int* __restrict__ csr,
                                               const float* __restrict__ dinv,
                                               const float* __restrict__ bias,
                                               const float* __restrict__ x1,
                                               const float* __restrict__ Wn,
                                               unsigned short* __restrict__ zout,
                                               int N) {
    __shared__ float xs[4][68];
    __shared__ float4 wt4[1024];  // Wn [64][64] staged row-major
    const int tid = threadIdx.x;
    const int lane = tid & 63;
    const int wid = tid >> 6;
    const int c0 = blockIdx.x * 4;
    const int c = c0 + wid;

#pragma unroll
    for (int v = 0; v < 4; ++v)
        wt4[v * 256 + tid] = *reinterpret_cast<const float4*>(Wn + (size_t)(v * 256 + tid) * 4);

    if (c < N) {
        int s = __builtin_amdgcn_readfirstlane(offs[c]);
        int e = __builtin_amdgcn_readfirstlane(offs[c + 1]);
        const int half = lane >> 5;
        const int d = lane & 31;
        const unsigned* __restrict__ zr = (const unsigned*)z;

        float ax = 0.f, ay = 0.f;
        if (half == 0) {
            unsigned sv = zr[(size_t)c * 32 + d];
            ax = bf2f((unsigned short)(sv & 0xffffu));
            ay = bf2f((unsigned short)(sv >> 16));
        }
        float ux[8] = {0, 0, 0, 0, 0, 0, 0, 0};
        float uy[8] = {0, 0, 0, 0, 0, 0, 0, 0};
        int j = s;
        for (; j + 16 <= e; j += 16) {
#pragma unroll
            for (int u = 0; u < 8; ++u) {
                int r0 = csr[j + 2 * u];
                int r1 = csr[j + 2 * u + 1];
                int r = half ? r1 : r0;
                unsigned v = zr[(size_t)r * 32 + d];
                ux[u] += bf2f((unsigned short)(v & 0xffffu));
                uy[u] += bf2f((unsigned short)(v >> 16));
            }
        }
        for (; j + 2 <= e; j += 2) {
            int r0 = csr[j];
            int r1 = csr[j + 1];
            int r = half ? r1 : r0;
            unsigned v = zr[(size_t)r * 32 + d];
            ax += bf2f((unsigned short)(v & 0xffffu));
            ay += bf2f((unsigned short)(v >> 16));
        }
        if (j < e && half == 0) {
            int r = csr[j];
            unsigned v = zr[(size_t)r * 32 + d];
            ax += bf2f((unsigned short)(v & 0xffffu));
            ay += bf2f((unsigned short)(v >> 16));
        }
        float tx = ax + ((ux[0] + ux[1]) + (ux[2] + ux[3])) + ((ux[4] + ux[5]) + (ux[6] + ux[7]));
        float ty = ay + ((uy[0] + uy[1]) + (uy[2] + uy[3])) + ((uy[4] + uy[5]) + (uy[6] + uy[7]));
        tx += __shfl_xor(tx, 32);
        ty += __shfl_xor(ty, 32);
        if (half == 0) {
            float dv = dinv[c];
            float2 bb = reinterpret_cast<const float2*>(bias)[d];
            float2 xx = *reinterpret_cast<const float2*>(x1 + (size_t)c * 64 + 2 * d);
            xs[wid][2 * d] = dv * tx + bb.x + xx.x;
            xs[wid][2 * d + 1] = dv * ty + bb.y + xx.y;
        }
    }
    __syncthreads();

    // mm phase: thread = (node n = tid>>6, col j = lane)
    {
        int n = wid;
        int cn = c0 + n;
        if (cn < N) {
            const float* W = (const float*)wt4;
            float y = 0.f;
#pragma unroll
            for (int k = 0; k < 64; ++k)
                y = fmaf(xs[n][k], W[k * 64 + lane], y);
            zout[(size_t)cn * 64 + lane] = f2bf(y * dinv[cn]);
        }
    }
}

// ---------------------------------------------------------------------------
// Fused layer-3 aggregate + head: x4 = agg + bg3 + x1; h = leaky(x4@Wo1+bo1);
// out = sigmoid(h@Wo2+bo2).
__global__ __launch_bounds__(256) void k_agghead(const unsigned short* __restrict__ z,
                                                 const int* __restrict__ offs,
                                                 const int* __restrict__ csr,
                                                 const float* __restrict__ dinv,
                                                 const float* __restrict__ bias,
                                                 const float* __restrict__ x1,
                                                 const float* __restrict__ Wo1,
                                                 const float* __restrict__ bo1,
                                                 const float* __restrict__ Wo2,
                                                 const float* __restrict__ bo2,
                                                 float* __restrict__ out, int N) {
    __shared__ float xs[4][68];
    __shared__ float hs[4][68];
    __shared__ float4 wt4[1024];  // Wo1
    __shared__ float wo2[128];
    __shared__ float bo1s[64];
    const int tid = threadIdx.x;
    const int lane = tid & 63;
    const int wid = tid >> 6;
    const int c0 = blockIdx.x * 4;
    const int c = c0 + wid;

#pragma unroll
    for (int v = 0; v < 4; ++v)
        wt4[v * 256 + tid] = *reinterpret_cast<const float4*>(Wo1 + (size_t)(v * 256 + tid) * 4);
    if (tid < 128) wo2[tid] = Wo2[tid];
    if (tid < 64) bo1s[tid] = bo1[tid];

    if (c < N) {
        int s = __builtin_amdgcn_readfirstlane(offs[c]);
        int e = __builtin_amdgcn_readfirstlane(offs[c + 1]);
        const int half = lane >> 5;
        const int d = lane & 31;
        const unsigned* __restrict__ zr = (const unsigned*)z;

        float ax = 0.f, ay = 0.f;
        if (half == 0) {
            unsigned sv = zr[(size_t)c * 32 + d];
            ax = bf2f((unsigned short)(sv & 0xffffu));
            ay = bf2f((unsigned short)(sv >> 16));
        }
        float ux[8] = {0, 0, 0, 0, 0, 0, 0, 0};
        float uy[8] = {0, 0, 0, 0, 0, 0, 0, 0};
        int j = s;
        for (; j + 16 <= e; j += 16) {
#pragma unroll
            for (int u = 0; u < 8; ++u) {
                int r0 = csr[j + 2 * u];
                int r1 = csr[j + 2 * u + 1];
                int r = half ? r1 : r0;
                unsigned v = zr[(size_t)r * 32 + d];
                ux[u] += bf2f((unsigned short)(v & 0xffffu));
                uy[u] += bf2f((unsigned short)(v >> 16));
            }
        }
        for (; j + 2 <= e; j += 2) {
            int r0 = csr[j];
            int r1 = csr[j + 1];
            int r = half ? r1 : r0;
            unsigned v = zr[(size_t)r * 32 + d];
            ax += bf2f((unsigned short)(v & 0xffffu));
            ay += bf2f((unsigned short)(v >> 16));
        }
        if (j < e && half == 0) {
            int r = csr[j];
            unsigned v = zr[(size_t)r * 32 + d];
            ax += bf2f((unsigned short)(v & 0xffffu));
            ay += bf2f((unsigned short)(v >> 16));
        }
        float tx = ax + ((ux[0] + ux[1]) + (ux[2] + ux[3])) + ((ux[4] + ux[5]) + (ux[6] + ux[7]));
        float ty = ay + ((uy[0] + uy[1]) + (uy[2] + uy[3])) + ((uy[4] + uy[5]) + (uy[6] + uy[7]));
        tx += __shfl_xor(tx, 32);
        ty += __shfl_xor(ty, 32);
        if (half == 0) {
            float dv = dinv[c];
            float2 bb = reinterpret_cast<const float2*>(bias)[d];
            float2 xx = *reinterpret_cast<const float2*>(x1 + (size_t)c * 64 + 2 * d);
            xs[wid][2 * d] = dv * tx + bb.x + xx.x;
            xs[wid][2 * d + 1] = dv * ty + bb.y + xx.y;
        }
    }
    __syncthreads();

    // head mm1: h[n][j] = leaky(sum_k xs[n][k]*Wo1[k][j] + bo1[j])
    {
        int n = wid;
        const float* W = (const float*)wt4;
        float y = bo1s[lane];
#pragma unroll
        for (int k = 0; k < 64; ++k)
            y = fmaf(xs[n][k], W[k * 64 + lane], y);
        hs[n][lane] = leaky(y);
    }
    __syncthreads();

    // head mm2: out[n][j2] = sigmoid(sum_k hs[n][k]*Wo2[k][j2] + bo2[j2])
    if (tid < 8) {
        int n = tid >> 1;
        int j2 = tid & 1;
        int cn = c0 + n;
        if (cn < N) {
            float a = bo2[j2];
#pragma unroll
            for (int k = 0; k < 64; ++k)
                a = fmaf(hs[n][k], wo2[k * 2 + j2], a);
            out[(size_t)cn * 2 + j2] = 1.f / (1.f + expf(-a));
        }
    }
}

// ---------------------------------------------------------------------------
extern "C" void kernel_launch(void* const* d_in, const int* in_sizes, int n_in,
                              void* d_out, int out_size, void* d_ws, size_t ws_size,
                              hipStream_t stream) {
    const float* screen   = (const float*)d_in[0];
    const float* des      = (const float*)d_in[1];
    const float* tweet    = (const float*)d_in[2];
    const float* profile  = (const float*)d_in[3];
    const float* personal = (const float*)d_in[4];
    const int*   edge     = (const int*)d_in[5];
    const float* Ws  = (const float*)d_in[6],  *bs  = (const float*)d_in[7];
    const float* Wd  = (const float*)d_in[8],  *bd  = (const float*)d_in[9];
    const float* Wt  = (const float*)d_in[10], *bt  = (const float*)d_in[11];
    const float* Wp  = (const float*)d_in[12], *bp  = (const float*)d_in[13];
    const float* Wpe = (const float*)d_in[14], *bpe = (const float*)d_in[15];
    const float* Wl  = (const float*)d_in[16], *bl  = (const float*)d_in[17];
    const float* Wg1 = (const float*)d_in[18], *bg1 = (const float*)d_in[19];
    const float* Wg2 = (const float*)d_in[20], *bg2 = (const float*)d_in[21];
    const float* Wg3 = (const float*)d_in[22], *bg3 = (const float*)d_in[23];
    const float* Wo1 = (const float*)d_in[24], *bo1 = (const float*)d_in[25];
    const float* Wo2 = (const float*)d_in[26], *bo2 = (const float*)d_in[27];

    const int N = in_sizes[0] / 768;   // 50000
    const int E = in_sizes[5] / 2;     // 1600000
    const int* row = edge;
    const int* col = edge + E;

    size_t off = 0;
    auto alloc = [&](size_t bytes) -> void* {
        void* p = (char*)d_ws + off;
        off += (bytes + 255) & ~(size_t)255;
        return p;
    };
    const size_t NF = (size_t)N * 64;
    float* x1   = (float*)alloc(NF * 4);
    unsigned short* za = (unsigned short*)alloc(NF * 2);
    unsigned short* zb = (unsigned short*)alloc(NF * 2);
    float* dinv = (float*)alloc((size_t)N * 4);
    int* deg  = (int*)alloc((size_t)N * 4);
    int* part = (int*)alloc((size_t)N * 4);
    int* offs = (int*)alloc((size_t)(N + 1) * 4);
    int* pos  = (int*)alloc((size_t)N * 4);
    int* csr  = (int*)alloc((size_t)E * 4);
    const int NB = (N + 255) / 256;
    int* bsum = (int*)alloc((size_t)NB * 4);
    int* boff = (int*)alloc((size_t)NB * 4);
    (void)ws_size; (void)n_in; (void)out_size;

    hipMemsetAsync(deg, 0, (size_t)N * 4, stream);

    // Phase A: MFMA feature linears + tiny linears, deg atomics inlined
    const int NG = (N + 127) / 128;
    const int NSM = (N + 511) / 512;
    k_featB<<<NG * 3 + NSM, 512, 0, stream>>>(screen, des, tweet,
                                              Ws, bs, Wd, bd, Wt, bt,
                                              profile, personal, Wp, bp, Wpe, bpe,
                                              col, deg, E,
                                              x1, N, NG, NSM);

    // degree scan -> offs, pos, dinv
    k_scan_part<<<NB, 256, 0, stream>>>(deg, part, bsum, N);
    k_scan_sums<<<1, 256, 0, stream>>>(bsum, boff, NB, offs + N);
    k_scan_final<<<NB, 256, 0, stream>>>(part, boff, deg, offs, pos, dinv, N);

    const int NGB = (N + 63) / 64;
    const int NAB = (N + 3) / 4;
    // layer 1 lin+matmul fused, CSR fill inlined -> za
    k_lin1<<<NGB, 256, 0, stream>>>(x1, Wl, bl, Wg1, dinv,
                                    row, col, pos, csr, E, za, N, NGB);
    // layer 1 agg + layer 2 matmul -> zb
    k_aggmm<<<NAB, 256, 0, stream>>>(za, offs, csr, dinv, bg1, x1, Wg2, zb, N);
    // layer 2 agg + layer 3 matmul -> za
    k_aggmm<<<NAB, 256, 0, stream>>>(zb, offs, csr, dinv, bg2, x1, Wg3, za, N);
    // layer 3 agg + head -> out
    k_agghead<<<NAB, 256, 0, stream>>>(za, offs, csr, dinv, bg3, x1,
                                       Wo1, bo1, Wo2, bo2, (float*)d_out, N);
}

// Round 14
// 398.122 us; speedup vs baseline: 1.3323x; 1.0185x over previous
//
#include <hip/hip_runtime.h>

__device__ __forceinline__ float leaky(float v) { return v >= 0.f ? v : 0.01f * v; }

__device__ __forceinline__ void fma4(float4& a, float s, const float4& w) {
    a.x = fmaf(s, w.x, a.x); a.y = fmaf(s, w.y, a.y);
    a.z = fmaf(s, w.z, a.z); a.w = fmaf(s, w.w, a.w);
}

__device__ __forceinline__ unsigned short f2bf(float x) {  // RNE
    unsigned b = __float_as_uint(x);
    return (unsigned short)((b + 0x7FFFu + ((b >> 16) & 1u)) >> 16);
}
__device__ __forceinline__ float bf2f(unsigned short u) {
    return __uint_as_float(((unsigned)u) << 16);
}

typedef __attribute__((ext_vector_type(8))) short short8v;
typedef __attribute__((ext_vector_type(4))) float float4v;

// ---------------------------------------------------------------------------
// Scan kernels (unchanged)
__global__ __launch_bounds__(256) void k_scan_part(const int* __restrict__ deg,
                                                   int* __restrict__ part,
                                                   int* __restrict__ bsum, int N) {
    __shared__ int tmp[256];
    int tid = threadIdx.x;
    int i = blockIdx.x * 256 + tid;
    int v = (i < N) ? deg[i] : 0;
    tmp[tid] = v;
    __syncthreads();
    for (int ofs = 1; ofs < 256; ofs <<= 1) {
        int t = (tid >= ofs) ? tmp[tid - ofs] : 0;
        __syncthreads();
        tmp[tid] += t;
        __syncthreads();
    }
    int incl = tmp[tid];
    if (i < N) part[i] = incl - v;
    if (tid == 255) bsum[blockIdx.x] = incl;
}

__global__ __launch_bounds__(256) void k_scan_sums(const int* __restrict__ bsum,
                                                   int* __restrict__ boff, int NB,
                                                   int* __restrict__ offs_last) {
    __shared__ int tmp[256];
    int tid = threadIdx.x;
    int v = (tid < NB) ? bsum[tid] : 0;
    tmp[tid] = v;
    __syncthreads();
    for (int ofs = 1; ofs < 256; ofs <<= 1) {
        int t = (tid >= ofs) ? tmp[tid - ofs] : 0;
        __syncthreads();
        tmp[tid] += t;
        __syncthreads();
    }
    int incl = tmp[tid];
    if (tid < NB) boff[tid] = incl - v;
    if (tid == 255) offs_last[0] = incl;
}

__global__ __launch_bounds__(256) void k_scan_final(const int* __restrict__ part,
                                                    const int* __restrict__ boff,
                                                    const int* __restrict__ deg,
                                                    int* __restrict__ offs,
                                                    int* __restrict__ pos,
                                                    float* __restrict__ dinv, int N) {
    int i = blockIdx.x * 256 + threadIdx.x;
    if (i < N) {
        int o = part[i] + boff[blockIdx.x];
        offs[i] = o;
        pos[i] = o;
        dinv[i] = rsqrtf((float)(deg[i] + 1));
    }
}

// ---------------------------------------------------------------------------
// Phase A — MFMA featB with ASM-forced 4-deep prefetch ring (counted vmcnt,
// never 0 mid-loop) + tiny linears + inlined degree atomics.
__global__ __launch_bounds__(512) void k_featB(
    const float* __restrict__ s, const float* __restrict__ d, const float* __restrict__ t,
    const float* __restrict__ Ws, const float* __restrict__ bs2,
    const float* __restrict__ Wd, const float* __restrict__ bd2,
    const float* __restrict__ Wt, const float* __restrict__ bt2,
    const float* __restrict__ prof, const float* __restrict__ pers,
    const float* __restrict__ Wp, const float* __restrict__ bp,
    const float* __restrict__ Wpe, const float* __restrict__ bpe,
    const int* __restrict__ colv, int* __restrict__ deg, int E,
    float* __restrict__ x1g, int N, int NG, int NSM) {
    __shared__ short8v wfv[3072];  // [hi:1536][lo:1536] fragments, 48 KB

    const int bid = blockIdx.x;
    const int tid = threadIdx.x;

    {   // fused degree atomics (fire-and-forget; drained by the barrier below)
        const int NW = 3 * NG + NSM;
        int eper = (E + NW - 1) / NW;
        int ebase = bid * eper;
        int eend = ebase + eper; if (eend > E) eend = E;
        for (int e = ebase + tid; e < eend; e += 512)
            atomicAdd(&deg[colv[e]], 1);
    }

    if (bid >= 3 * NG) {  // fused tiny linears
        int n = (bid - 3 * NG) * 512 + tid;
        if (n >= N) return;
        float pv[5], pe[7];
#pragma unroll
        for (int i = 0; i < 5; ++i) pv[i] = prof[(size_t)n * 5 + i];
#pragma unroll
        for (int i = 0; i < 7; ++i) pe[i] = pers[(size_t)n * 7 + i];
        float o[16];
#pragma unroll
        for (int j = 0; j < 8; ++j) {
            float a = bp[j];
#pragma unroll
            for (int i = 0; i < 5; ++i) a = fmaf(pv[i], Wp[i * 8 + j], a);
            o[j] = leaky(a);
            float a2 = bpe[j];
#pragma unroll
            for (int i = 0; i < 7; ++i) a2 = fmaf(pe[i], Wpe[i * 8 + j], a2);
            o[8 + j] = leaky(a2);
        }
#pragma unroll
        for (int v = 0; v < 4; ++v)
            *reinterpret_cast<float4*>(x1g + (size_t)n * 64 + 48 + v * 4) =
                make_float4(o[v * 4], o[v * 4 + 1], o[v * 4 + 2], o[v * 4 + 3]);
        return;
    }

    const int f = bid / NG;
    const int grp = bid - f * NG;
    const float* __restrict__ X = (f == 0) ? s : ((f == 1) ? d : t);
    const float* __restrict__ W = (f == 0) ? Ws : ((f == 1) ? Wd : Wt);
    const float* __restrict__ B = (f == 0) ? bs2 : ((f == 1) ? bd2 : bt2);
    const int n0 = grp * 128;
    const int lane = tid & 63;
    const int wid = tid >> 6;  // 0..7

    short* wfs = (short*)wfv;
#pragma unroll
    for (int v = 0; v < 6; ++v) {
        int idx4 = tid + v * 512;
        float4 w4 = *reinterpret_cast<const float4*>(W + (size_t)idx4 * 4);
        int k = idx4 >> 2;
        int j0 = (idx4 & 3) * 4;
        int c = k >> 5, g = (k >> 3) & 3, i = k & 7;
        float wq[4] = {w4.x, w4.y, w4.z, w4.w};
#pragma unroll
        for (int q = 0; q < 4; ++q) {
            int sl = (c * 64 + g * 16 + j0 + q) * 8 + i;
            unsigned short h = f2bf(wq[q]);
            wfs[sl] = (short)h;
            wfs[12288 + sl] = (short)f2bf(wq[q] - bf2f(h));
        }
    }
    __syncthreads();   // drains vmcnt(0) -> counted scheme below is exact

    const int nb = n0 + wid * 16;
    int mrow = nb + (lane & 15); if (mrow >= N) mrow = N - 1;
    const float* base = X + (size_t)mrow * 768 + ((lane >> 4) << 3);

    float4 pa[4], pb[4];
    float4v acc = {0.f, 0.f, 0.f, 0.f};

    // asm loads cannot be sunk/collapsed by the allocator (R8-R12: VGPR=40
    // proved the C++ ring was always de-pipelined). offsets are literals.
#define ISSUE_LD(u, c) \
    asm volatile("global_load_dwordx4 %0, %1, off offset:%c2" \
                 : "=v"(pa[u]) : "v"(base), "i"((c) * 128)); \
    asm volatile("global_load_dwordx4 %0, %1, off offset:%c2" \
                 : "=v"(pb[u]) : "v"(base), "i"((c) * 128 + 16));

    ISSUE_LD(0, 0) ISSUE_LD(1, 1) ISSUE_LD(2, 2) ISSUE_LD(3, 3)

#define CHUNK(c) { \
    asm volatile("s_waitcnt vmcnt(%c0)" :: "i"((23 - (c)) >= 3 ? 6 : 2 * (23 - (c)))); \
    __builtin_amdgcn_sched_barrier(0); \
    float xs[8] = {pa[(c) & 3].x, pa[(c) & 3].y, pa[(c) & 3].z, pa[(c) & 3].w, \
                   pb[(c) & 3].x, pb[(c) & 3].y, pb[(c) & 3].z, pb[(c) & 3].w}; \
    short8v xh, xl; \
    _Pragma("unroll") \
    for (int i = 0; i < 8; ++i) { \
        unsigned short h = f2bf(xs[i]); \
        xh[i] = (short)h; \
        xl[i] = (short)f2bf(xs[i] - bf2f(h)); \
    } \
    short8v wh = wfv[(c) * 64 + lane]; \
    short8v wl = wfv[1536 + (c) * 64 + lane]; \
    acc = __builtin_amdgcn_mfma_f32_16x16x32_bf16(xh, wh, acc, 0, 0, 0); \
    acc = __builtin_amdgcn_mfma_f32_16x16x32_bf16(xl, wh, acc, 0, 0, 0); \
    acc = __builtin_amdgcn_mfma_f32_16x16x32_bf16(xh, wl, acc, 0, 0, 0); \
    if ((c) + 4 < 24) { ISSUE_LD((c) & 3, (c) + 4) } }

    CHUNK(0)  CHUNK(1)  CHUNK(2)  CHUNK(3)  CHUNK(4)  CHUNK(5)
    CHUNK(6)  CHUNK(7)  CHUNK(8)  CHUNK(9)  CHUNK(10) CHUNK(11)
    CHUNK(12) CHUNK(13) CHUNK(14) CHUNK(15) CHUNK(16) CHUNK(17)
    CHUNK(18) CHUNK(19) CHUNK(20) CHUNK(21) CHUNK(22) CHUNK(23)
#undef CHUNK
#undef ISSUE_LD

    int j = lane & 15;
    float bb = B[j];
#pragma unroll
    for (int r = 0; r < 4; ++r) {
        int n = nb + ((lane >> 4) << 2) + r;
        if (n < N) x1g[(size_t)n * 64 + f * 16 + j] = leaky(acc[r] + bb);
    }
}

// ---------------------------------------------------------------------------
// Fused lin + gcn1-matmul + inlined CSR fill (unchanged R13). Writes z (bf16).
__global__ __launch_bounds__(256) void k_lin1(const float* __restrict__ x1,
                                              const float* __restrict__ Wl,
                                              const float* __restrict__ bl,
                                              const float* __restrict__ Wg1,
                                              const float* __restrict__ dinvv,
                                              const int* __restrict__ rowv,
                                              const int* __restrict__ colv,
                                              int* __restrict__ pos,
                                              int* __restrict__ csr, int E,
                                              unsigned short* __restrict__ z,
                                              int N, int NGB) {
    __shared__ float4 xt4[1024];
    __shared__ float4 wt4[1024];
    const int tid = threadIdx.x;
    const int bid = blockIdx.x;

    {   // fused CSR fill prologue
        int eper = (E + NGB - 1) / NGB;
        int ebase = bid * eper;
        int eend = ebase + eper; if (eend > E) eend = E;
        int cols[8], rows[8];
#pragma unroll
        for (int r = 0; r < 8; ++r) {
            int e = ebase + tid + r * 256;
            cols[r] = (e < eend) ? colv[e] : -1;
            rows[r] = (e < eend) ? rowv[e] : 0;
        }
        int ps[8];
#pragma unroll
        for (int r = 0; r < 8; ++r)
            if (cols[r] >= 0) ps[r] = atomicAdd(&pos[cols[r]], 1);
#pragma unroll
        for (int r = 0; r < 8; ++r)
            if (cols[r] >= 0) csr[ps[r]] = rows[r];
    }

    const int n0 = bid * 64;
    const int nq = tid & 15;
    const int jq = tid >> 4;

#pragma unroll
    for (int v = 0; v < 4; ++v) {
        int L = v * 256 + tid;
        int n = L >> 4, c4 = L & 15;
        int nn = n0 + n; if (nn >= N) nn = N - 1;
        xt4[n * 16 + (c4 ^ (n & 15))] = *reinterpret_cast<const float4*>(x1 + (size_t)nn * 64 + c4 * 4);
        wt4[L] = *reinterpret_cast<const float4*>(Wl + (size_t)L * 4);
    }
    __syncthreads();

    float4 acc[4];
#pragma unroll
    for (int g = 0; g < 4; ++g) acc[g] = make_float4(0.f, 0.f, 0.f, 0.f);
    for (int k = 0; k < 64; k += 4) {
        float4 w0 = wt4[(k + 0) * 16 + jq];
        float4 w1 = wt4[(k + 1) * 16 + jq];
        float4 w2 = wt4[(k + 2) * 16 + jq];
        float4 w3 = wt4[(k + 3) * 16 + jq];
        int k4 = k >> 2;
#pragma unroll
        for (int g = 0; g < 4; ++g) {
            int n = nq + (g << 4);
            float4 xv = xt4[n * 16 + (k4 ^ (n & 15))];
            fma4(acc[g], xv.x, w0);
            fma4(acc[g], xv.y, w1);
            fma4(acc[g], xv.z, w2);
            fma4(acc[g], xv.w, w3);
        }
    }
    float4 bb = *reinterpret_cast<const float4*>(bl + jq * 4);
    __syncthreads();

#pragma unroll
    for (int g = 0; g < 4; ++g) {
        int n = nq + (g << 4);
        float4 h;
        h.x = leaky(acc[g].x + bb.x);
        h.y = leaky(acc[g].y + bb.y);
        h.z = leaky(acc[g].z + bb.z);
        h.w = leaky(acc[g].w + bb.w);
        xt4[n * 16 + (jq ^ (n & 15))] = h;
    }
#pragma unroll
    for (int v = 0; v < 4; ++v) {
        int L = v * 256 + tid;
        wt4[L] = *reinterpret_cast<const float4*>(Wg1 + (size_t)L * 4);
    }
    __syncthreads();

#pragma unroll
    for (int g = 0; g < 4; ++g) acc[g] = make_float4(0.f, 0.f, 0.f, 0.f);
    for (int k = 0; k < 64; k += 4) {
        float4 w0 = wt4[(k + 0) * 16 + jq];
        float4 w1 = wt4[(k + 1) * 16 + jq];
        float4 w2 = wt4[(k + 2) * 16 + jq];
        float4 w3 = wt4[(k + 3) * 16 + jq];
        int k4 = k >> 2;
#pragma unroll
        for (int g = 0; g < 4; ++g) {
            int n = nq + (g << 4);
            float4 xv = xt4[n * 16 + (k4 ^ (n & 15))];
            fma4(acc[g], xv.x, w0);
            fma4(acc[g], xv.y, w1);
            fma4(acc[g], xv.z, w2);
            fma4(acc[g], xv.w, w3);
        }
    }
#pragma unroll
    for (int g = 0; g < 4; ++g) {
        int n = nq + (g << 4);
        if (n0 + n >= N) continue;
        float dv = dinvv[n0 + n];
        ushort4 o;
        o.x = f2bf(acc[g].x * dv); o.y = f2bf(acc[g].y * dv);
        o.z = f2bf(acc[g].z * dv); o.w = f2bf(acc[g].w * dv);
        *reinterpret_cast<ushort4*>(z + (size_t)(n0 + n) * 64 + jq * 4) = o;
    }
}

// ---------------------------------------------------------------------------
// Fused aggregate + next-layer matmul (unchanged R13).
__global__ __launch_bounds__(256) void k_aggmm(const unsigned short* __restrict__ z,
                                               const int* __restrict__ offs,
                                               const int* __restrict__ csr,
                                               const float* __restrict__ dinv,
                                               const float* __restrict__ bias,
                                               const float* __restrict__ x1,
                                               const float* __restrict__ Wn,
                                               unsigned short* __restrict__ zout,
                                               int N) {
    __shared__ float xs[4][68];
    __shared__ float4 wt4[1024];  // Wn [64][64] staged row-major
    const int tid = threadIdx.x;
    const int lane = tid & 63;
    const int wid = tid >> 6;
    const int c0 = blockIdx.x * 4;
    const int c = c0 + wid;

#pragma unroll
    for (int v = 0; v < 4; ++v)
        wt4[v * 256 + tid] = *reinterpret_cast<const float4*>(Wn + (size_t)(v * 256 + tid) * 4);

    if (c < N) {
        int s = __builtin_amdgcn_readfirstlane(offs[c]);
        int e = __builtin_amdgcn_readfirstlane(offs[c + 1]);
        const int half = lane >> 5;
        const int d = lane & 31;
        const unsigned* __restrict__ zr = (const unsigned*)z;

        float ax = 0.f, ay = 0.f;
        if (half == 0) {
            unsigned sv = zr[(size_t)c * 32 + d];
            ax = bf2f((unsigned short)(sv & 0xffffu));
            ay = bf2f((unsigned short)(sv >> 16));
        }
        float ux[8] = {0, 0, 0, 0, 0, 0, 0, 0};
        float uy[8] = {0, 0, 0, 0, 0, 0, 0, 0};
        int j = s;
        for (; j + 16 <= e; j += 16) {
#pragma unroll
            for (int u = 0; u < 8; ++u) {
                int r0 = csr[j + 2 * u];
                int r1 = csr[j + 2 * u + 1];
                int r = half ? r1 : r0;
                unsigned v = zr[(size_t)r * 32 + d];
                ux[u] += bf2f((unsigned short)(v & 0xffffu));
                uy[u] += bf2f((unsigned short)(v >> 16));
            }
        }
        for (; j + 2 <= e; j += 2) {
            int r0 = csr[j];
            int r1 = csr[j + 1];
            int r = half ? r1 : r0;
            unsigned v = zr[(size_t)r * 32 + d];
            ax += bf2f((unsigned short)(v & 0xffffu));
            ay += bf2f((unsigned short)(v >> 16));
        }
        if (j < e && half == 0) {
            int r = csr[j];
            unsigned v = zr[(size_t)r * 32 + d];
            ax += bf2f((unsigned short)(v & 0xffffu));
            ay += bf2f((unsigned short)(v >> 16));
        }
        float tx = ax + ((ux[0] + ux[1]) + (ux[2] + ux[3])) + ((ux[4] + ux[5]) + (ux[6] + ux[7]));
        float ty = ay + ((uy[0] + uy[1]) + (uy[2] + uy[3])) + ((uy[4] + uy[5]) + (uy[6] + uy[7]));
        tx += __shfl_xor(tx, 32);
        ty += __shfl_xor(ty, 32);
        if (half == 0) {
            float dv = dinv[c];
            float2 bb = reinterpret_cast<const float2*>(bias)[d];
            float2 xx = *reinterpret_cast<const float2*>(x1 + (size_t)c * 64 + 2 * d);
            xs[wid][2 * d] = dv * tx + bb.x + xx.x;
            xs[wid][2 * d + 1] = dv * ty + bb.y + xx.y;
        }
    }
    __syncthreads();

    {   // mm phase
        int n = wid;
        int cn = c0 + n;
        if (cn < N) {
            const float* W = (const float*)wt4;
            float y = 0.f;
#pragma unroll
            for (int k = 0; k < 64; ++k)
                y = fmaf(xs[n][k], W[k * 64 + lane], y);
            zout[(size_t)cn * 64 + lane] = f2bf(y * dinv[cn]);
        }
    }
}

// ---------------------------------------------------------------------------
// Fused layer-3 aggregate + head (unchanged R13).
__global__ __launch_bounds__(256) void k_agghead(const unsigned short* __restrict__ z,
                                                 const int* __restrict__ offs,
                                                 const int* __restrict__ csr,
                                                 const float* __restrict__ dinv,
                                                 const float* __restrict__ bias,
                                                 const float* __restrict__ x1,
                                                 const float* __restrict__ Wo1,
                                                 const float* __restrict__ bo1,
                                                 const float* __restrict__ Wo2,
                                                 const float* __restrict__ bo2,
                                                 float* __restrict__ out, int N) {
    __shared__ float xs[4][68];
    __shared__ float hs[4][68];
    __shared__ float4 wt4[1024];  // Wo1
    __shared__ float wo2[128];
    __shared__ float bo1s[64];
    const int tid = threadIdx.x;
    const int lane = tid & 63;
    const int wid = tid >> 6;
    const int c0 = blockIdx.x * 4;
    const int c = c0 + wid;

#pragma unroll
    for (int v = 0; v < 4; ++v)
        wt4[v * 256 + tid] = *reinterpret_cast<const float4*>(Wo1 + (size_t)(v * 256 + tid) * 4);
    if (tid < 128) wo2[tid] = Wo2[tid];
    if (tid < 64) bo1s[tid] = bo1[tid];

    if (c < N) {
        int s = __builtin_amdgcn_readfirstlane(offs[c]);
        int e = __builtin_amdgcn_readfirstlane(offs[c + 1]);
        const int half = lane >> 5;
        const int d = lane & 31;
        const unsigned* __restrict__ zr = (const unsigned*)z;

        float ax = 0.f, ay = 0.f;
        if (half == 0) {
            unsigned sv = zr[(size_t)c * 32 + d];
            ax = bf2f((unsigned short)(sv & 0xffffu));
            ay = bf2f((unsigned short)(sv >> 16));
        }
        float ux[8] = {0, 0, 0, 0, 0, 0, 0, 0};
        float uy[8] = {0, 0, 0, 0, 0, 0, 0, 0};
        int j = s;
        for (; j + 16 <= e; j += 16) {
#pragma unroll
            for (int u = 0; u < 8; ++u) {
                int r0 = csr[j + 2 * u];
                int r1 = csr[j + 2 * u + 1];
                int r = half ? r1 : r0;
                unsigned v = zr[(size_t)r * 32 + d];
                ux[u] += bf2f((unsigned short)(v & 0xffffu));
                uy[u] += bf2f((unsigned short)(v >> 16));
            }
        }
        for (; j + 2 <= e; j += 2) {
            int r0 = csr[j];
            int r1 = csr[j + 1];
            int r = half ? r1 : r0;
            unsigned v = zr[(size_t)r * 32 + d];
            ax += bf2f((unsigned short)(v & 0xffffu));
            ay += bf2f((unsigned short)(v >> 16));
        }
        if (j < e && half == 0) {
            int r = csr[j];
            unsigned v = zr[(size_t)r * 32 + d];
            ax += bf2f((unsigned short)(v & 0xffffu));
            ay += bf2f((unsigned short)(v >> 16));
        }
        float tx = ax + ((ux[0] + ux[1]) + (ux[2] + ux[3])) + ((ux[4] + ux[5]) + (ux[6] + ux[7]));
        float ty = ay + ((uy[0] + uy[1]) + (uy[2] + uy[3])) + ((uy[4] + uy[5]) + (uy[6] + uy[7]));
        tx += __shfl_xor(tx, 32);
        ty += __shfl_xor(ty, 32);
        if (half == 0) {
            float dv = dinv[c];
            float2 bb = reinterpret_cast<const float2*>(bias)[d];
            float2 xx = *reinterpret_cast<const float2*>(x1 + (size_t)c * 64 + 2 * d);
            xs[wid][2 * d] = dv * tx + bb.x + xx.x;
            xs[wid][2 * d + 1] = dv * ty + bb.y + xx.y;
        }
    }
    __syncthreads();

    {   // head mm1
        int n = wid;
        const float* W = (const float*)wt4;
        float y = bo1s[lane];
#pragma unroll
        for (int k = 0; k < 64; ++k)
            y = fmaf(xs[n][k], W[k * 64 + lane], y);
        hs[n][lane] = leaky(y);
    }
    __syncthreads();

    if (tid < 8) {  // head mm2 + sigmoid
        int n = tid >> 1;
        int j2 = tid & 1;
        int cn = c0 + n;
        if (cn < N) {
            float a = bo2[j2];
#pragma unroll
            for (int k = 0; k < 64; ++k)
                a = fmaf(hs[n][k], wo2[k * 2 + j2], a);
            out[(size_t)cn * 2 + j2] = 1.f / (1.f + expf(-a));
        }
    }
}

// ---------------------------------------------------------------------------
extern "C" void kernel_launch(void* const* d_in, const int* in_sizes, int n_in,
                              void* d_out, int out_size, void* d_ws, size_t ws_size,
                              hipStream_t stream) {
    const float* screen   = (const float*)d_in[0];
    const float* des      = (const float*)d_in[1];
    const float* tweet    = (const float*)d_in[2];
    const float* profile  = (const float*)d_in[3];
    const float* personal = (const float*)d_in[4];
    const int*   edge     = (const int*)d_in[5];
    const float* Ws  = (const float*)d_in[6],  *bs  = (const float*)d_in[7];
    const float* Wd  = (const float*)d_in[8],  *bd  = (const float*)d_in[9];
    const float* Wt  = (const float*)d_in[10], *bt  = (const float*)d_in[11];
    const float* Wp  = (const float*)d_in[12], *bp  = (const float*)d_in[13];
    const float* Wpe = (const float*)d_in[14], *bpe = (const float*)d_in[15];
    const float* Wl  = (const float*)d_in[16], *bl  = (const float*)d_in[17];
    const float* Wg1 = (const float*)d_in[18], *bg1 = (const float*)d_in[19];
    const float* Wg2 = (const float*)d_in[20], *bg2 = (const float*)d_in[21];
    const float* Wg3 = (const float*)d_in[22], *bg3 = (const float*)d_in[23];
    const float* Wo1 = (const float*)d_in[24], *bo1 = (const float*)d_in[25];
    const float* Wo2 = (const float*)d_in[26], *bo2 = (const float*)d_in[27];

    const int N = in_sizes[0] / 768;   // 50000
    const int E = in_sizes[5] / 2;     // 1600000
    const int* row = edge;
    const int* col = edge + E;

    size_t off = 0;
    auto alloc = [&](size_t bytes) -> void* {
        void* p = (char*)d_ws + off;
        off += (bytes + 255) & ~(size_t)255;
        return p;
    };
    const size_t NF = (size_t)N * 64;
    float* x1   = (float*)alloc(NF * 4);
    unsigned short* za = (unsigned short*)alloc(NF * 2);
    unsigned short* zb = (unsigned short*)alloc(NF * 2);
    float* dinv = (float*)alloc((size_t)N * 4);
    int* deg  = (int*)alloc((size_t)N * 4);
    int* part = (int*)alloc((size_t)N * 4);
    int* offs = (int*)alloc((size_t)(N + 1) * 4);
    int* pos  = (int*)alloc((size_t)N * 4);
    int* csr  = (int*)alloc((size_t)E * 4);
    const int NB = (N + 255) / 256;
    int* bsum = (int*)alloc((size_t)NB * 4);
    int* boff = (int*)alloc((size_t)NB * 4);
    (void)ws_size; (void)n_in; (void)out_size;

    hipMemsetAsync(deg, 0, (size_t)N * 4, stream);

    // Phase A: MFMA feature linears + tiny linears, deg atomics inlined
    const int NG = (N + 127) / 128;
    const int NSM = (N + 511) / 512;
    k_featB<<<NG * 3 + NSM, 512, 0, stream>>>(screen, des, tweet,
                                              Ws, bs, Wd, bd, Wt, bt,
                                              profile, personal, Wp, bp, Wpe, bpe,
                                              col, deg, E,
                                              x1, N, NG, NSM);

    // degree scan -> offs, pos, dinv
    k_scan_part<<<NB, 256, 0, stream>>>(deg, part, bsum, N);
    k_scan_sums<<<1, 256, 0, stream>>>(bsum, boff, NB, offs + N);
    k_scan_final<<<NB, 256, 0, stream>>>(part, boff, deg, offs, pos, dinv, N);

    const int NGB = (N + 63) / 64;
    const int NAB = (N + 3) / 4;
    // layer 1 lin+matmul fused, CSR fill inlined -> za
    k_lin1<<<NGB, 256, 0, stream>>>(x1, Wl, bl, Wg1, dinv,
                                    row, col, pos, csr, E, za, N, NGB);
    // layer 1 agg + layer 2 matmul -> zb
    k_aggmm<<<NAB, 256, 0, stream>>>(za, offs, csr, dinv, bg1, x1, Wg2, zb, N);
    // layer 2 agg + layer 3 matmul -> za
    k_aggmm<<<NAB, 256, 0, stream>>>(zb, offs, csr, dinv, bg2, x1, Wg3, za, N);
    // layer 3 agg + head -> out
    k_agghead<<<NAB, 256, 0, stream>>>(za, offs, csr, dinv, bg3, x1,
                                       Wo1, bo1, Wo2, bo2, (float*)d_out, N);
}